// Round 5
// baseline (498.808 us; speedup 1.0000x reference)
//
#include <hip/hip_runtime.h>
#include <hip/hip_bf16.h>

#define EPSV 1e-5f
#define PSHIFT 6            // partition = 64 nodes
#define PMASK 63
#define PCAP 1536           // per-partition staging cap (mean 1024, +16 sigma)
#define B1SHIFT 11          // coarse bucket = 2048 nodes = 32 partitions
#define B1MASK ((1 << B1SHIFT) - 1)
#define B1CAP 34816         // per-bucket cap (mean 32768, +11 sigma)
#define SPLIT 16            // scatter2 blocks per coarse bucket

typedef __attribute__((ext_vector_type(8))) short bf16x8;
typedef __attribute__((ext_vector_type(4))) float f32x4;
typedef __attribute__((ext_vector_type(4))) unsigned u32x4;

__device__ __forceinline__ float bf2f(unsigned short u) {
    unsigned x = ((unsigned)u) << 16;
    return __builtin_bit_cast(float, x);
}
__device__ __forceinline__ unsigned short f2bf(float f) {
    unsigned x = __builtin_bit_cast(unsigned, f);
    unsigned r = (x + 0x7fffu + ((x >> 16) & 1u)) >> 16;  // RNE
    return (unsigned short)r;
}
// even features (low bf16 of each u32): just shift into place
__device__ __forceinline__ f32x4 bflo4(u32x4 v) {
    f32x4 r;
    r.x = __builtin_bit_cast(float, v.x << 16);
    r.y = __builtin_bit_cast(float, v.y << 16);
    r.z = __builtin_bit_cast(float, v.z << 16);
    r.w = __builtin_bit_cast(float, v.w << 16);
    return r;
}
// odd features (high bf16): mask only
__device__ __forceinline__ f32x4 bfhi4(u32x4 v) {
    f32x4 r;
    r.x = __builtin_bit_cast(float, v.x & 0xffff0000u);
    r.y = __builtin_bit_cast(float, v.y & 0xffff0000u);
    r.z = __builtin_bit_cast(float, v.z & 0xffff0000u);
    r.w = __builtin_bit_cast(float, v.w & 0xffff0000u);
    return r;
}

// ---------------- two-level LDS-ranked scatter (R8, verified -42us) ----------------

// level 1: edges -> 49 coarse buckets (2048 nodes each). val=(s<<11)|(d&2047).
__global__ __launch_bounds__(256) void k_scatter1(const int* __restrict__ src,
                                                  const int* __restrict__ dst,
                                                  int* __restrict__ bcnt1,
                                                  unsigned* __restrict__ stg1,
                                                  int E, int NB1) {
    __shared__ int hist[64], sbase[64], scur[64];
    int t = threadIdx.x;
    int base = blockIdx.x * 2048;
    if (t < 64) { hist[t] = 0; scur[t] = 0; }
    __syncthreads();
    unsigned val[8];
    int cb[8];
#pragma unroll
    for (int k = 0; k < 8; k++) {
        int i = base + k * 256 + t;
        if (i < E) {
            int d = __builtin_nontemporal_load(&dst[i]);
            int s = __builtin_nontemporal_load(&src[i]);
            cb[k] = d >> B1SHIFT;
            val[k] = ((unsigned)s << B1SHIFT) | (unsigned)(d & B1MASK);
            atomicAdd(&hist[cb[k]], 1);
        } else
            cb[k] = -1;
    }
    __syncthreads();
    if (t < NB1 && hist[t] > 0) sbase[t] = atomicAdd(&bcnt1[t], hist[t]);
    __syncthreads();
#pragma unroll
    for (int k = 0; k < 8; k++) {
        if (cb[k] >= 0) {
            int r = atomicAdd(&scur[cb[k]], 1);
            int slot = sbase[cb[k]] + r;
            if (slot < B1CAP) stg1[(size_t)cb[k] * B1CAP + slot] = val[k];
        }
    }
}

// level 2: coarse bucket -> 32 partitions inside it. out val=(s<<6)|(d&63).
__global__ __launch_bounds__(256) void k_scatter2(const int* __restrict__ bcnt1,
                                                  const unsigned* __restrict__ stg1,
                                                  int* __restrict__ pcnt,
                                                  unsigned* __restrict__ pstg) {
    __shared__ int hist[32], sbase[32], scur[32];
    int cb = blockIdx.x >> 4;  // / SPLIT
    int sl = blockIdx.x & (SPLIT - 1);
    int t = threadIdx.x;
    if (t < 32) { hist[t] = 0; scur[t] = 0; }
    int cnt = min(bcnt1[cb], B1CAP);
    int per = (cnt + SPLIT - 1) / SPLIT;
    int lo = sl * per, hi = min(lo + per, cnt);
    __syncthreads();
    const unsigned* sp = stg1 + (size_t)cb * B1CAP;
    for (int j = lo + t; j < hi; j += 256)
        atomicAdd(&hist[(sp[j] >> 6) & 31], 1);
    __syncthreads();
    if (t < 32 && hist[t] > 0) sbase[t] = atomicAdd(&pcnt[(cb << 5) + t], hist[t]);
    __syncthreads();
    for (int j = lo + t; j < hi; j += 256) {
        unsigned v = sp[j];
        int pr = (v >> 6) & 31;  // d bits 6..10 = partition within bucket
        int r = atomicAdd(&scur[pr], 1);
        int slot = sbase[pr] + r;
        if (slot < PCAP)
            pstg[(size_t)((cb << 5) + pr) * PCAP + slot] =
                ((v >> 5) & ~63u) | (v & 63u);  // (s<<6)|(d&63)
    }
}

// block 0: partition totals + exclusive scan -> pbase, off[N]=total
// block 1: graph bounds from sorted batch (binary search)
__global__ __launch_bounds__(256) void k_meta(const int* __restrict__ pcnt,
                                              int* __restrict__ pbase,
                                              int* __restrict__ off,
                                              const int* __restrict__ batch,
                                              int* __restrict__ gstart,
                                              int NPART, int Nn, int G) {
    if (blockIdx.x == 1) {
        int g = threadIdx.x;
        if (g > G) return;
        if (g == G) {
            gstart[G] = Nn;
            return;
        }
        int lo = 0, hi = Nn;
        while (lo < hi) {
            int mid = (lo + hi) >> 1;
            if (batch[mid] < g) lo = mid + 1;
            else hi = mid;
        }
        gstart[g] = lo;
        return;
    }
    __shared__ int red[256];
    int t = threadIdx.x;
    int chunk = (NPART + 255) / 256;
    int lo = t * chunk, hi = min(lo + chunk, NPART);
    int s = 0;
    for (int p = lo; p < hi; p++) {
        int tt = min(pcnt[p], PCAP);
        pbase[p] = tt;  // temp: totals
        s += tt;
    }
    red[t] = s;
    __syncthreads();
    for (int d = 1; d < 256; d <<= 1) {
        int v = (t >= d) ? red[t - d] : 0;
        __syncthreads();
        red[t] += v;
        __syncthreads();
    }
    int base = (t == 0) ? 0 : red[t - 1];
    for (int p = lo; p < hi; p++) {
        int tt = pbase[p];
        pbase[p] = base;
        base += tt;
    }
    if (t == 255) off[Nn] = red[255];
}

__global__ __launch_bounds__(256) void k_build(const int* __restrict__ pcnt,
                                               const unsigned* __restrict__ pstg,
                                               const int* __restrict__ pbase,
                                               int* __restrict__ off,
                                               int* __restrict__ csr, int Nn) {
    __shared__ unsigned ed[PCAP];
    __shared__ int srt[PCAP];
    __shared__ int cnt[64], loff[64], cur[64];
    int p = blockIdx.x, t = threadIdx.x;
    int tot = min(pcnt[p], PCAP);
    if (t < 64) cnt[t] = 0;
    __syncthreads();
    const unsigned* sp = pstg + (size_t)p * PCAP;
    for (int j = t; j < tot; j += 256) {
        unsigned e = __builtin_nontemporal_load(&sp[j]);
        ed[j] = e;
        atomicAdd(&cnt[e & PMASK], 1);
    }
    __syncthreads();
    if (t == 0) {
        int a = 0;
        for (int j = 0; j < 64; j++) {
            loff[j] = a;
            cur[j] = a;
            a += cnt[j];
        }
    }
    __syncthreads();
    int base = pbase[p];
    int node0 = p << PSHIFT;
    if (t < 64 && node0 + t < Nn) off[node0 + t] = base + loff[t];
    for (int j = t; j < tot; j += 256) {
        unsigned e = ed[j];
        int pos = atomicAdd(&cur[e & PMASK], 1);
        srt[pos] = (int)(e >> PSHIFT);
    }
    __syncthreads();
    for (int j = t; j < tot; j += 256) csr[base + j] = srt[j];
}

// ---------------- layer-0 aggregation (din=7) ----------------

__global__ __launch_bounds__(256) void k_agg7(const float* __restrict__ x,
                                              const int* __restrict__ off,
                                              const int* __restrict__ csr,
                                              float* __restrict__ mean, int n) {
    int i = (blockIdx.x * 256 + threadIdx.x) >> 3;
    int r = threadIdx.x & 7;
    if (i >= n) return;
    int a = off[i], b = off[i + 1];
    float acc = 0.f;
    if (r < 7) {
        int j = a;
        for (; j + 1 < b; j += 2)
            acc += x[(size_t)csr[j] * 7 + r] + x[(size_t)csr[j + 1] * 7 + r];
        if (j < b) acc += x[(size_t)csr[j] * 7 + r];
    }
    float inv = 1.0f / (float)max(b - a, 1);
    if (r < 7) mean[(size_t)i * 7 + r] = acc * inv;
}

// ---------------- weight prep: all 4 matrices in one launch ----------------

__global__ __launch_bounds__(256) void k_prepw_all(
    const float* __restrict__ Wl1, const float* __restrict__ Wr1,
    const float* __restrict__ Wl2, const float* __restrict__ Wr2,
    unsigned short* __restrict__ Wlt1, unsigned short* __restrict__ Wrt1,
    unsigned short* __restrict__ Wlt2, unsigned short* __restrict__ Wrt2) {
    int u = blockIdx.x * 256 + threadIdx.x;
    const float* W;
    unsigned short* Wt;
    int Ncols, v;
    if (u < 32768) {
        v = u & 16383;
        W = (u < 16384) ? Wl1 : Wr1;
        Wt = (u < 16384) ? Wlt1 : Wrt1;
        Ncols = 128;
    } else {
        v = (u - 32768) & 32767;
        W = (u < 65536) ? Wl2 : Wr2;
        Wt = (u < 65536) ? Wlt2 : Wrt2;
        Ncols = 256;
    }
    int n = v % Ncols, k = v / Ncols;
    Wt[(size_t)n * 128 + k] = f2bf(W[(size_t)k * Ncols + n]);
}

// ---------------- layer 0 (din=7, fp32 vector) -> bf16 out ----------------

__global__ __launch_bounds__(256) void k_layer0(
    const float* __restrict__ x, const float* __restrict__ mean,
    const float* __restrict__ Wl, const float* __restrict__ bl,
    const float* __restrict__ Wr, const float* __restrict__ g,
    const float* __restrict__ be, const float* __restrict__ rm,
    const float* __restrict__ rv, unsigned short* __restrict__ out, int n) {
    int tid = threadIdx.x;
    int col = tid & 127;
    int r = tid >> 7;
    int row = blockIdx.x * 2 + r;
    if (row >= n) return;
    float sc = g[col] * rsqrtf(rv[col] + EPSV);
    float sh = (bl[col] - rm[col]) * sc + be[col];
    const float* xp = x + (size_t)row * 7;
    const float* mp = mean + (size_t)row * 7;
    float acc = 0.f;
#pragma unroll
    for (int k = 0; k < 7; k++) acc += xp[k] * Wl[k * 128 + col];
#pragma unroll
    for (int k = 0; k < 7; k++) acc += mp[k] * Wr[k * 128 + col];
    float h = acc * sc + sh;
    out[(size_t)row * 128 + col] = f2bf(fmaxf(h, 0.f));
}

// ---------------- fused gather + MFMA layer (R12) ----------------
// Rationale: agg128 is pinned at ~3.4 TB/s L2-fill (8 XCDs x 25.6 MB, random
// graph -> no locality; R1/R4 identical rate). During the gather the MFMA/VALU
// pipes idle, so the GEMM rides along for free via inter-block overlap.
// Each block: (1) gather/mean its 64 rows into Ms (LDS, full K=128),
// (2) 8-stage MFMA loop; pass 0 A from global xin (staged to As), pass 1 A
// read directly from Ms. Saves the meanb global round-trip (50 MB) and 2
// dispatches. Layer 1: COLS=128 -> bf16 x2 (NOT in-place: gathers read
// foreign rows). Layer 2: COLS=256 -> fp32 x3 (single block column, no
// grid.y, else gather traffic doubles).

template <int COLS, bool BF16OUT>
__global__ __launch_bounds__(256) void k_fused_layer(
    const unsigned short* __restrict__ xin,
    const int* __restrict__ off, const int* __restrict__ csr,
    const unsigned short* __restrict__ Wlt, const unsigned short* __restrict__ Wrt,
    const float* __restrict__ bl, const float* __restrict__ g,
    const float* __restrict__ be, const float* __restrict__ rm,
    const float* __restrict__ rv, void* __restrict__ outv, int n) {
    __shared__ unsigned short Ms[64 * 136];  // mean rows, full K, stride 136
    __shared__ unsigned short As[64 * 40];
    __shared__ unsigned short Bs[COLS * 40];

    int tid = threadIdx.x;
    int wave = tid >> 6;
    int lane = tid & 63;
    int m = lane & 15;
    int half = lane >> 4;
    int row0 = blockIdx.x * 64;

    // ---- phase 1: gather means. 16 quarter-waves x 4 rows each.
    {
        int qw = tid >> 4;
        int sl = tid & 15;
        const u32x4* xr = (const u32x4*)xin;  // 16 x 16B per 128-col row
        for (int r4 = 0; r4 < 4; r4++) {
            int row = qw * 4 + r4;
            int grow = row0 + row;
            f32x4 aL = {0.f, 0.f, 0.f, 0.f}, aH = {0.f, 0.f, 0.f, 0.f};
            float inv = 0.f;
            if (grow < n) {
                int a = off[grow], b = off[grow + 1];
                int j = a;
                for (; j + 3 < b; j += 4) {
                    int s0 = csr[j], s1 = csr[j + 1], s2 = csr[j + 2], s3 = csr[j + 3];
                    u32x4 v0 = xr[(size_t)s0 * 16 + sl];
                    u32x4 v1 = xr[(size_t)s1 * 16 + sl];
                    u32x4 v2 = xr[(size_t)s2 * 16 + sl];
                    u32x4 v3 = xr[(size_t)s3 * 16 + sl];
                    aL += bflo4(v0) + bflo4(v1) + bflo4(v2) + bflo4(v3);
                    aH += bfhi4(v0) + bfhi4(v1) + bfhi4(v2) + bfhi4(v3);
                }
                for (; j < b; j++) {
                    u32x4 v = xr[(size_t)csr[j] * 16 + sl];
                    aL += bflo4(v);
                    aH += bfhi4(v);
                }
                inv = 1.0f / (float)max(b - a, 1);
            }
            u32x4 o;
            o.x = (unsigned)f2bf(aL.x * inv) | ((unsigned)f2bf(aH.x * inv) << 16);
            o.y = (unsigned)f2bf(aL.y * inv) | ((unsigned)f2bf(aH.y * inv) << 16);
            o.z = (unsigned)f2bf(aL.z * inv) | ((unsigned)f2bf(aH.z * inv) << 16);
            o.w = (unsigned)f2bf(aL.w * inv) | ((unsigned)f2bf(aH.w * inv) << 16);
            *(u32x4*)&Ms[row * 136 + sl * 8] = o;
        }
    }

    // ---- phase 2: MFMA over K = 2x128 (pass 0: xin @ Wl, pass 1: Ms @ Wr)
    const int NCB = COLS / 16;
    f32x4 acc[NCB] = {};
    int rr = tid >> 2;
    int ks = (tid & 3) * 8;

    for (int s = 0; s < 8; s++) {
        int pass = s >> 2;
        int k0 = (s & 3) * 32;
        const unsigned short* Wt = pass ? Wrt : Wlt;

        __syncthreads();  // (first iter: also closes the gather phase)
        if (pass == 0) {  // stage A: 64 rows x 32 k from xin
            int grow = row0 + rr;
            float4 v = make_float4(0.f, 0.f, 0.f, 0.f);
            if (grow < n) v = *(const float4*)&xin[(size_t)grow * 128 + k0 + ks];
            *(float4*)&As[rr * 40 + ks] = v;
        }
#pragma unroll
        for (int rep = 0; rep < COLS / 64; rep++) {  // stage B: COLS cols x 32 k
            int u = tid + rep * 256;
            int nn = u >> 2;
            int ks2 = (u & 3) * 8;
            float4 v = *(const float4*)&Wt[(size_t)nn * 128 + k0 + ks2];
            *(float4*)&Bs[nn * 40 + ks2] = v;
        }
        __syncthreads();

        bf16x8 a;
        if (pass == 0)
            a = *(const bf16x8*)&As[(wave * 16 + m) * 40 + half * 8];
        else
            a = *(const bf16x8*)&Ms[(wave * 16 + m) * 136 + k0 + half * 8];
#pragma unroll
        for (int cb = 0; cb < NCB; cb++) {
            bf16x8 b = *(const bf16x8*)&Bs[(cb * 16 + m) * 40 + half * 8];
            acc[cb] = __builtin_amdgcn_mfma_f32_16x16x32_bf16(a, b, acc[cb], 0, 0, 0);
        }
    }

    float* outf = (float*)outv;
    unsigned short* outb = (unsigned short*)outv;
#pragma unroll
    for (int cb = 0; cb < NCB; cb++) {
        int col = cb * 16 + m;
        float sc = g[col] * rsqrtf(rv[col] + EPSV);
        float sh = (bl[col] - rm[col]) * sc + be[col];
#pragma unroll
        for (int reg = 0; reg < 4; reg++) {
            int r0 = row0 + wave * 16 + half * 4 + reg;
            if (r0 < n) {
                float h = fmaxf(acc[cb][reg] * sc + sh, 0.f);
                if (BF16OUT) outb[(size_t)r0 * COLS + col] = f2bf(h);
                else outf[(size_t)r0 * COLS + col] = h;
            }
        }
    }
}

// ---------------- pooling ----------------

__global__ __launch_bounds__(256) void k_pool(const float* __restrict__ x3,
                                              const int* __restrict__ gstart,
                                              float* __restrict__ pooled, int G) {
    const int S = 16;
    int g = blockIdx.x / S;
    int s = blockIdx.x % S;
    int a = gstart[g], b = gstart[g + 1];
    int col = threadIdx.x;
    float acc = 0.f;
    for (int r = a + s; r < b; r += S) acc += x3[(size_t)r * 256 + col];
    atomicAdd(&pooled[g * 256 + col], acc);
}

// ---------------- launch ----------------

extern "C" void kernel_launch(void* const* d_in, const int* in_sizes, int n_in,
                              void* d_out, int out_size, void* d_ws, size_t ws_size,
                              hipStream_t stream) {
    const float* x = (const float*)d_in[0];
    const int* ei = (const int*)d_in[1];
    const int* batch = (const int*)d_in[2];
    const int N = in_sizes[0] / 7;
    const int E = in_sizes[1] / 2;
    const int G = 64;
    const int* src = ei;
    const int* dst = ei + E;
    const int NPART = (N + PMASK) >> PSHIFT;
    const int NB1 = (N + (1 << B1SHIFT) - 1) >> B1SHIFT;

    const float* P[21];
    for (int i = 0; i < 21; i++) P[i] = (const float*)d_in[3 + i];
    const float **L0 = P, **L1 = P + 7, **L2 = P + 14;

    char* w = (char*)d_ws;
    auto carve = [&](size_t bytes) {
        void* p = (void*)w;
        w += (bytes + 255) & ~(size_t)255;
        return p;
    };
    int* cnts = (int*)carve((size_t)(64 + NPART) * 4);  // bcnt1[64] + pcnt[NPART]
    int* bcnt1 = cnts;
    int* pcnt = cnts + 64;
    unsigned* stg1 = (unsigned*)carve((size_t)NB1 * B1CAP * 4);
    unsigned* pstg = (unsigned*)carve((size_t)NPART * PCAP * 4);
    int* pbase = (int*)carve((size_t)NPART * 4);
    int* off = (int*)carve(((size_t)N + 1) * 4);
    int* gstart = (int*)carve(((size_t)G + 1) * 4);
    float* mean7 = (float*)carve((size_t)N * 7 * 4);
    unsigned short* x1 = (unsigned short*)carve((size_t)N * 128 * 2);
    unsigned short* x2 = (unsigned short*)carve((size_t)N * 128 * 2);
    unsigned short* Wlt1 = (unsigned short*)carve((size_t)128 * 128 * 2);
    unsigned short* Wrt1 = (unsigned short*)carve((size_t)128 * 128 * 2);
    unsigned short* Wlt2 = (unsigned short*)carve((size_t)128 * 256 * 2);
    unsigned short* Wrt2 = (unsigned short*)carve((size_t)128 * 256 * 2);
    // csr aliases stg1: stg1 is dead after k_scatter2 completes, and k_build
    // (same stream) is the first writer of csr.
    int* csr = (int*)stg1;

    float* pooled = (float*)d_out;
    float* x3 = (float*)d_out + (size_t)G * 256;

    hipMemsetAsync(cnts, 0, (size_t)(64 + NPART) * 4, stream);
    hipMemsetAsync(pooled, 0, (size_t)G * 256 * 4, stream);

    // CSR build: two-level LDS-ranked scatter + meta + partition sort
    k_scatter1<<<(E + 2047) / 2048, 256, 0, stream>>>(src, dst, bcnt1, stg1, E, NB1);
    k_scatter2<<<NB1 * SPLIT, 256, 0, stream>>>(bcnt1, stg1, pcnt, pstg);
    k_meta<<<2, 256, 0, stream>>>(pcnt, pbase, off, batch, gstart, NPART, N, G);
    k_build<<<NPART, 256, 0, stream>>>(pcnt, pstg, pbase, off, csr, N);
    k_prepw_all<<<(98304 + 255) / 256, 256, 0, stream>>>(L1[0], L1[2], L2[0], L2[2],
                                                         Wlt1, Wrt1, Wlt2, Wrt2);

    // layer 0: din=7 -> 128 (fp32 vector, bf16 out)
    k_agg7<<<(N * 8 + 255) / 256, 256, 0, stream>>>(x, off, csr, mean7, N);
    k_layer0<<<(N + 1) / 2, 256, 0, stream>>>(x, mean7, L0[0], L0[1], L0[2], L0[3],
                                              L0[4], L0[5], L0[6], x1, N);

    // layer 1: fused gather+MFMA, 128 -> 128, bf16 out to x2
    k_fused_layer<128, true><<<(N + 63) / 64, 256, 0, stream>>>(
        x1, off, csr, Wlt1, Wrt1, L1[1], L1[3], L1[4], L1[5], L1[6], x2, N);

    // layer 2: fused gather+MFMA, 128 -> 256, fp32 out into d_out x-region
    k_fused_layer<256, false><<<(N + 63) / 64, 256, 0, stream>>>(
        x2, off, csr, Wlt2, Wrt2, L2[1], L2[3], L2[4], L2[5], L2[6], x3, N);

    // global add pool
    k_pool<<<G * 16, 256, 0, stream>>>(x3, gstart, pooled, G);
}

// Round 6
// 496.338 us; speedup vs baseline: 1.0050x; 1.0050x over previous
//
#include <hip/hip_runtime.h>
#include <hip/hip_bf16.h>

#define EPSV 1e-5f
#define PSHIFT 6            // partition = 64 nodes
#define PMASK 63
#define PCAP 1536           // per-partition staging cap (mean 1024, +16 sigma)
#define B1SHIFT 11          // coarse bucket = 2048 nodes = 32 partitions
#define B1MASK ((1 << B1SHIFT) - 1)
#define B1CAP 34816         // per-bucket cap (mean 32768, +11 sigma)
#define SPLIT 16            // scatter2 blocks per coarse bucket

typedef __attribute__((ext_vector_type(8))) short bf16x8;
typedef __attribute__((ext_vector_type(4))) float f32x4;
typedef __attribute__((ext_vector_type(4))) unsigned u32x4;

__device__ __forceinline__ float bf2f(unsigned short u) {
    unsigned x = ((unsigned)u) << 16;
    return __builtin_bit_cast(float, x);
}
__device__ __forceinline__ unsigned short f2bf(float f) {
    unsigned x = __builtin_bit_cast(unsigned, f);
    unsigned r = (x + 0x7fffu + ((x >> 16) & 1u)) >> 16;  // RNE
    return (unsigned short)r;
}
__device__ __forceinline__ f32x4 bflo4(u32x4 v) {
    f32x4 r;
    r.x = __builtin_bit_cast(float, v.x << 16);
    r.y = __builtin_bit_cast(float, v.y << 16);
    r.z = __builtin_bit_cast(float, v.z << 16);
    r.w = __builtin_bit_cast(float, v.w << 16);
    return r;
}
__device__ __forceinline__ f32x4 bfhi4(u32x4 v) {
    f32x4 r;
    r.x = __builtin_bit_cast(float, v.x & 0xffff0000u);
    r.y = __builtin_bit_cast(float, v.y & 0xffff0000u);
    r.z = __builtin_bit_cast(float, v.z & 0xffff0000u);
    r.w = __builtin_bit_cast(float, v.w & 0xffff0000u);
    return r;
}

// ---------------- two-level LDS-ranked scatter (R8, verified -42us) ----------------

__global__ __launch_bounds__(256) void k_scatter1(const int* __restrict__ src,
                                                  const int* __restrict__ dst,
                                                  int* __restrict__ bcnt1,
                                                  unsigned* __restrict__ stg1,
                                                  int E, int NB1) {
    __shared__ int hist[64], sbase[64], scur[64];
    int t = threadIdx.x;
    int base = blockIdx.x * 2048;
    if (t < 64) { hist[t] = 0; scur[t] = 0; }
    __syncthreads();
    unsigned val[8];
    int cb[8];
#pragma unroll
    for (int k = 0; k < 8; k++) {
        int i = base + k * 256 + t;
        if (i < E) {
            int d = __builtin_nontemporal_load(&dst[i]);
            int s = __builtin_nontemporal_load(&src[i]);
            cb[k] = d >> B1SHIFT;
            val[k] = ((unsigned)s << B1SHIFT) | (unsigned)(d & B1MASK);
            atomicAdd(&hist[cb[k]], 1);
        } else
            cb[k] = -1;
    }
    __syncthreads();
    if (t < NB1 && hist[t] > 0) sbase[t] = atomicAdd(&bcnt1[t], hist[t]);
    __syncthreads();
#pragma unroll
    for (int k = 0; k < 8; k++) {
        if (cb[k] >= 0) {
            int r = atomicAdd(&scur[cb[k]], 1);
            int slot = sbase[cb[k]] + r;
            if (slot < B1CAP) stg1[(size_t)cb[k] * B1CAP + slot] = val[k];
        }
    }
}

__global__ __launch_bounds__(256) void k_scatter2(const int* __restrict__ bcnt1,
                                                  const unsigned* __restrict__ stg1,
                                                  int* __restrict__ pcnt,
                                                  unsigned* __restrict__ pstg) {
    __shared__ int hist[32], sbase[32], scur[32];
    int cb = blockIdx.x >> 4;  // / SPLIT
    int sl = blockIdx.x & (SPLIT - 1);
    int t = threadIdx.x;
    if (t < 32) { hist[t] = 0; scur[t] = 0; }
    int cnt = min(bcnt1[cb], B1CAP);
    int per = (cnt + SPLIT - 1) / SPLIT;
    int lo = sl * per, hi = min(lo + per, cnt);
    __syncthreads();
    const unsigned* sp = stg1 + (size_t)cb * B1CAP;
    for (int j = lo + t; j < hi; j += 256)
        atomicAdd(&hist[(sp[j] >> 6) & 31], 1);
    __syncthreads();
    if (t < 32 && hist[t] > 0) sbase[t] = atomicAdd(&pcnt[(cb << 5) + t], hist[t]);
    __syncthreads();
    for (int j = lo + t; j < hi; j += 256) {
        unsigned v = sp[j];
        int pr = (v >> 6) & 31;
        int r = atomicAdd(&scur[pr], 1);
        int slot = sbase[pr] + r;
        if (slot < PCAP)
            pstg[(size_t)((cb << 5) + pr) * PCAP + slot] =
                ((v >> 5) & ~63u) | (v & 63u);  // (s<<6)|(d&63)
    }
}

__global__ __launch_bounds__(256) void k_meta(const int* __restrict__ pcnt,
                                              int* __restrict__ pbase,
                                              int* __restrict__ off,
                                              const int* __restrict__ batch,
                                              int* __restrict__ gstart,
                                              int NPART, int Nn, int G) {
    if (blockIdx.x == 1) {
        int g = threadIdx.x;
        if (g > G) return;
        if (g == G) {
            gstart[G] = Nn;
            return;
        }
        int lo = 0, hi = Nn;
        while (lo < hi) {
            int mid = (lo + hi) >> 1;
            if (batch[mid] < g) lo = mid + 1;
            else hi = mid;
        }
        gstart[g] = lo;
        return;
    }
    __shared__ int red[256];
    int t = threadIdx.x;
    int chunk = (NPART + 255) / 256;
    int lo = t * chunk, hi = min(lo + chunk, NPART);
    int s = 0;
    for (int p = lo; p < hi; p++) {
        int tt = min(pcnt[p], PCAP);
        pbase[p] = tt;  // temp: totals
        s += tt;
    }
    red[t] = s;
    __syncthreads();
    for (int d = 1; d < 256; d <<= 1) {
        int v = (t >= d) ? red[t - d] : 0;
        __syncthreads();
        red[t] += v;
        __syncthreads();
    }
    int base = (t == 0) ? 0 : red[t - 1];
    for (int p = lo; p < hi; p++) {
        int tt = pbase[p];
        pbase[p] = base;
        base += tt;
    }
    if (t == 255) off[Nn] = red[255];
}

__global__ __launch_bounds__(256) void k_build(const int* __restrict__ pcnt,
                                               const unsigned* __restrict__ pstg,
                                               const int* __restrict__ pbase,
                                               int* __restrict__ off,
                                               int* __restrict__ csr, int Nn) {
    __shared__ unsigned ed[PCAP];
    __shared__ int srt[PCAP];
    __shared__ int cnt[64], loff[64], cur[64];
    int p = blockIdx.x, t = threadIdx.x;
    int tot = min(pcnt[p], PCAP);
    if (t < 64) cnt[t] = 0;
    __syncthreads();
    const unsigned* sp = pstg + (size_t)p * PCAP;
    for (int j = t; j < tot; j += 256) {
        unsigned e = __builtin_nontemporal_load(&sp[j]);
        ed[j] = e;
        atomicAdd(&cnt[e & PMASK], 1);
    }
    __syncthreads();
    if (t == 0) {
        int a = 0;
        for (int j = 0; j < 64; j++) {
            loff[j] = a;
            cur[j] = a;
            a += cnt[j];
        }
    }
    __syncthreads();
    int base = pbase[p];
    int node0 = p << PSHIFT;
    if (t < 64 && node0 + t < Nn) off[node0 + t] = base + loff[t];
    for (int j = t; j < tot; j += 256) {
        unsigned e = ed[j];
        int pos = atomicAdd(&cur[e & PMASK], 1);
        srt[pos] = (int)(e >> PSHIFT);
    }
    __syncthreads();
    for (int j = t; j < tot; j += 256) csr[base + j] = srt[j];
}

// ---------------- aggregation ----------------

__global__ __launch_bounds__(256) void k_agg7(const float* __restrict__ x,
                                              const int* __restrict__ off,
                                              const int* __restrict__ csr,
                                              float* __restrict__ mean, int n) {
    int i = (blockIdx.x * 256 + threadIdx.x) >> 3;
    int r = threadIdx.x & 7;
    if (i >= n) return;
    int a = off[i], b = off[i + 1];
    float acc = 0.f;
    if (r < 7) {
        int j = a;
        for (; j + 1 < b; j += 2)
            acc += x[(size_t)csr[j] * 7 + r] + x[(size_t)csr[j + 1] * 7 + r];
        if (j < b) acc += x[(size_t)csr[j] * 7 + r];
    }
    float inv = 1.0f / (float)max(b - a, 1);
    if (r < 7) mean[(size_t)i * 7 + r] = acc * inv;
}

// R13 = R9's best-measured gather (60.6us): 16 lanes/node, 16B loads, 4-deep,
// plain csr loads, plain cacheable store. (8-deep + NT-csr measured worse in
// R4; NT mean-store suspected of forcing HBM re-fetch downstream.)
__global__ __launch_bounds__(256) void k_agg128(const unsigned short* __restrict__ x,
                                                const int* __restrict__ off,
                                                const int* __restrict__ csr,
                                                unsigned short* __restrict__ mean,
                                                int n) {
    int q = (blockIdx.x * 256 + threadIdx.x) >> 4;  // quarter-wave = node
    int sl = threadIdx.x & 15;
    if (q >= n) return;
    int a = off[q], b = off[q + 1];
    const u32x4* xr = (const u32x4*)x;  // 16 x 16B per 128-col row
    f32x4 aL = {0.f, 0.f, 0.f, 0.f}, aH = {0.f, 0.f, 0.f, 0.f};
    int j = a;
    for (; j + 3 < b; j += 4) {
        int s0 = csr[j], s1 = csr[j + 1], s2 = csr[j + 2], s3 = csr[j + 3];
        u32x4 v0 = xr[(size_t)s0 * 16 + sl];
        u32x4 v1 = xr[(size_t)s1 * 16 + sl];
        u32x4 v2 = xr[(size_t)s2 * 16 + sl];
        u32x4 v3 = xr[(size_t)s3 * 16 + sl];
        aL += bflo4(v0) + bflo4(v1) + bflo4(v2) + bflo4(v3);
        aH += bfhi4(v0) + bfhi4(v1) + bfhi4(v2) + bfhi4(v3);
    }
    for (; j < b; j++) {
        u32x4 v = xr[(size_t)csr[j] * 16 + sl];
        aL += bflo4(v);
        aH += bfhi4(v);
    }
    float inv = 1.0f / (float)max(b - a, 1);
    u32x4 o;
    o.x = (unsigned)f2bf(aL.x * inv) | ((unsigned)f2bf(aH.x * inv) << 16);
    o.y = (unsigned)f2bf(aL.y * inv) | ((unsigned)f2bf(aH.y * inv) << 16);
    o.z = (unsigned)f2bf(aL.z * inv) | ((unsigned)f2bf(aH.z * inv) << 16);
    o.w = (unsigned)f2bf(aL.w * inv) | ((unsigned)f2bf(aH.w * inv) << 16);
    *((u32x4*)mean + (size_t)q * 16 + sl) = o;
}

// ---------------- weight prep ----------------

__global__ __launch_bounds__(256) void k_prepw_all(
    const float* __restrict__ Wl1, const float* __restrict__ Wr1,
    const float* __restrict__ Wl2, const float* __restrict__ Wr2,
    unsigned short* __restrict__ Wlt1, unsigned short* __restrict__ Wrt1,
    unsigned short* __restrict__ Wlt2, unsigned short* __restrict__ Wrt2) {
    int u = blockIdx.x * 256 + threadIdx.x;
    const float* W;
    unsigned short* Wt;
    int Ncols, v;
    if (u < 32768) {
        v = u & 16383;
        W = (u < 16384) ? Wl1 : Wr1;
        Wt = (u < 16384) ? Wlt1 : Wrt1;
        Ncols = 128;
    } else {
        v = (u - 32768) & 32767;
        W = (u < 65536) ? Wl2 : Wr2;
        Wt = (u < 65536) ? Wlt2 : Wrt2;
        Ncols = 256;
    }
    int n = v % Ncols, k = v / Ncols;
    Wt[(size_t)n * 128 + k] = f2bf(W[(size_t)k * Ncols + n]);
}

// ---------------- layer 0 (din=7, fp32 vector) -> bf16 out ----------------

__global__ __launch_bounds__(256) void k_layer0(
    const float* __restrict__ x, const float* __restrict__ mean,
    const float* __restrict__ Wl, const float* __restrict__ bl,
    const float* __restrict__ Wr, const float* __restrict__ g,
    const float* __restrict__ be, const float* __restrict__ rm,
    const float* __restrict__ rv, unsigned short* __restrict__ out, int n) {
    int tid = threadIdx.x;
    int col = tid & 127;
    int r = tid >> 7;
    int row = blockIdx.x * 2 + r;
    if (row >= n) return;
    float sc = g[col] * rsqrtf(rv[col] + EPSV);
    float sh = (bl[col] - rm[col]) * sc + be[col];
    const float* xp = x + (size_t)row * 7;
    const float* mp = mean + (size_t)row * 7;
    float acc = 0.f;
#pragma unroll
    for (int k = 0; k < 7; k++) acc += xp[k] * Wl[k * 128 + col];
#pragma unroll
    for (int k = 0; k < 7; k++) acc += mp[k] * Wr[k * 128 + col];
    float h = acc * sc + sh;
    out[(size_t)row * 128 + col] = f2bf(fmaxf(h, 0.f));
}

// ---------------- MFMA layer (R11 core, unchanged) ----------------
// R13 addition (layer 2 only): atomic-FREE fused pooling. Each block
// LDS-reduces its per-graph column sums (<=2 graphs per 64-row block) and
// plain-stores them to disjoint wspool slots tagged with graph ids; k_poolred
// reduces. R2/R3 proved global-atomic flushes (400K-1M RMWs) are the failure
// mode -- this has zero global atomics on the fast path.

template <int COLS, int DOUT, bool BF16OUT>
__global__ __launch_bounds__(256) void k_mfma_layer(
    const unsigned short* __restrict__ xin, const unsigned short* __restrict__ meanb,
    const unsigned short* __restrict__ Wlt, const unsigned short* __restrict__ Wrt,
    const float* __restrict__ bl, const float* __restrict__ g,
    const float* __restrict__ be, const float* __restrict__ rm,
    const float* __restrict__ rv, void* __restrict__ outv,
    const int* __restrict__ batchp, const int* __restrict__ gstartp,
    int* __restrict__ wsgid, float* __restrict__ wspool,
    float* __restrict__ pooled, int n) {
    __shared__ unsigned short As[64 * 40];
    __shared__ unsigned short Bs[COLS * 40];
    __shared__ float plds[2 * COLS];

    int tid = threadIdx.x;
    int wave = tid >> 6;
    int lane = tid & 63;
    int m = lane & 15;
    int half = lane >> 4;
    int row0 = blockIdx.x * 64;
    int colbase = blockIdx.y * COLS;

    if (!BF16OUT)
        for (int u = tid; u < 2 * COLS; u += 256) plds[u] = 0.f;

    const int NCB = COLS / 16;
    f32x4 acc[NCB] = {};

    for (int s = 0; s < 8; s++) {
        int pass = s >> 2;
        int k0 = (s & 3) * 32;
        const unsigned short* Asrc = pass ? meanb : xin;
        const unsigned short* Wt = pass ? Wrt : Wlt;

        __syncthreads();
        {   // stage A: 64 rows x 32 k
            int rr = tid >> 2;
            int ks = (tid & 3) * 8;
            int grow = row0 + rr;
            float4 v = make_float4(0.f, 0.f, 0.f, 0.f);
            if (grow < n) v = *(const float4*)&Asrc[(size_t)grow * 128 + k0 + ks];
            *(float4*)&As[rr * 40 + ks] = v;
        }
#pragma unroll
        for (int rep = 0; rep < COLS / 64; rep++) {  // stage B: COLS cols x 32 k
            int u = tid + rep * 256;
            int nn = u >> 2;
            int ks = (u & 3) * 8;
            float4 v = *(const float4*)&Wt[(size_t)(colbase + nn) * 128 + k0 + ks];
            *(float4*)&Bs[nn * 40 + ks] = v;
        }
        __syncthreads();

        bf16x8 a = *(const bf16x8*)&As[(wave * 16 + m) * 40 + half * 8];
#pragma unroll
        for (int cb = 0; cb < NCB; cb++) {
            bf16x8 b = *(const bf16x8*)&Bs[(cb * 16 + m) * 40 + half * 8];
            acc[cb] = __builtin_amdgcn_mfma_f32_16x16x32_bf16(a, b, acc[cb], 0, 0, 0);
        }
    }

    // pooling setup (layer 2 only)
    int gA = 0, gB = 0, gsplit = 0x7fffffff;
    bool fast = true;
    if (!BF16OUT) {
        int last = min(row0 + 63, n - 1);
        gA = batchp[row0];
        gB = batchp[last];
        if (gB == gA + 1) gsplit = gstartp[gB];
        else if (gB != gA) fast = false;  // >2-graph span: absent in this data
    }

    float* outf = (float*)outv;
    unsigned short* outb = (unsigned short*)outv;
    float csA[NCB], csB[NCB];
#pragma unroll
    for (int cb = 0; cb < NCB; cb++) { csA[cb] = 0.f; csB[cb] = 0.f; }

#pragma unroll
    for (int cb = 0; cb < NCB; cb++) {
        int col = colbase + cb * 16 + m;
        float sc = g[col] * rsqrtf(rv[col] + EPSV);
        float sh = (bl[col] - rm[col]) * sc + be[col];
#pragma unroll
        for (int reg = 0; reg < 4; reg++) {
            int r0 = row0 + wave * 16 + half * 4 + reg;
            if (r0 < n) {
                float h = fmaxf(acc[cb][reg] * sc + sh, 0.f);
                if (BF16OUT) {
                    outb[(size_t)r0 * DOUT + col] = f2bf(h);
                } else {
                    outf[(size_t)r0 * DOUT + col] = h;
                    if (fast) {
                        if (r0 < gsplit) csA[cb] += h;
                        else csB[cb] += h;
                    } else {
                        atomicAdd(&pooled[(size_t)batchp[r0] * 256 + col], h);
                    }
                }
            }
        }
    }

    if (!BF16OUT) {
        bool two = (gsplit != 0x7fffffff);
        if (fast) {
#pragma unroll
            for (int cb = 0; cb < NCB; cb++) {
                atomicAdd(&plds[cb * 16 + m], csA[cb]);  // LDS atomics: cheap
                if (two) atomicAdd(&plds[COLS + cb * 16 + m], csB[cb]);
            }
        }
        __syncthreads();
        size_t bx = blockIdx.x;
        // disjoint plain stores; both grid.y blocks write their 128-col slice
        for (int u = tid; u < COLS; u += 256) {
            wspool[(bx * 2 + 0) * DOUT + colbase + u] = plds[u];
            wspool[(bx * 2 + 1) * DOUT + colbase + u] = plds[COLS + u];
        }
        if (tid < 2)
            wsgid[bx * 2 + tid] =
                !fast ? -1 : (tid == 0 ? gA : (two ? gB : -1));
    }
}

// ---------------- pooling reduction (atomic-free fast path) ----------------

__global__ __launch_bounds__(256) void k_poolred(const float* __restrict__ wspool,
                                                 const int* __restrict__ wsgid,
                                                 const int* __restrict__ gstart,
                                                 float* __restrict__ pooled) {
    int g = blockIdx.x;
    int col = threadIdx.x;
    int r0 = gstart[g], r1 = gstart[g + 1];
    if (r1 <= r0) return;
    int b0 = r0 >> 6, b1 = (r1 - 1) >> 6;
    float acc = 0.f;
    for (int bx = b0; bx <= b1; bx++) {
        int ga = wsgid[bx * 2], gb = wsgid[bx * 2 + 1];
        if (ga == g) acc += wspool[((size_t)bx * 2 + 0) * 256 + col];
        if (gb == g) acc += wspool[((size_t)bx * 2 + 1) * 256 + col];
    }
    atomicAdd(&pooled[(size_t)g * 256 + col], acc);  // composes with rare fallback
}

// ---------------- launch ----------------

extern "C" void kernel_launch(void* const* d_in, const int* in_sizes, int n_in,
                              void* d_out, int out_size, void* d_ws, size_t ws_size,
                              hipStream_t stream) {
    const float* x = (const float*)d_in[0];
    const int* ei = (const int*)d_in[1];
    const int* batch = (const int*)d_in[2];
    const int N = in_sizes[0] / 7;
    const int E = in_sizes[1] / 2;
    const int G = 64;
    const int* src = ei;
    const int* dst = ei + E;
    const int NPART = (N + PMASK) >> PSHIFT;
    const int NB1 = (N + (1 << B1SHIFT) - 1) >> B1SHIFT;
    const int NBX = (N + 63) / 64;

    const float* P[21];
    for (int i = 0; i < 21; i++) P[i] = (const float*)d_in[3 + i];
    const float **L0 = P, **L1 = P + 7, **L2 = P + 14;

    char* w = (char*)d_ws;
    auto carve = [&](size_t bytes) {
        void* p = (void*)w;
        w += (bytes + 255) & ~(size_t)255;
        return p;
    };
    int* cnts = (int*)carve((size_t)(64 + NPART) * 4);  // bcnt1[64] + pcnt[NPART]
    int* bcnt1 = cnts;
    int* pcnt = cnts + 64;
    unsigned* stg1 = (unsigned*)carve((size_t)NB1 * B1CAP * 4);
    unsigned* pstg = (unsigned*)carve((size_t)NPART * PCAP * 4);
    int* pbase = (int*)carve((size_t)NPART * 4);
    int* off = (int*)carve(((size_t)N + 1) * 4);
    int* gstart = (int*)carve(((size_t)G + 1) * 4);
    float* mean7 = (float*)carve((size_t)N * 7 * 4);
    unsigned short* x1 = (unsigned short*)carve((size_t)N * 128 * 2);
    unsigned short* meanb = (unsigned short*)carve((size_t)N * 128 * 2);
    unsigned short* Wlt1 = (unsigned short*)carve((size_t)128 * 128 * 2);
    unsigned short* Wrt1 = (unsigned short*)carve((size_t)128 * 128 * 2);
    unsigned short* Wlt2 = (unsigned short*)carve((size_t)128 * 256 * 2);
    unsigned short* Wrt2 = (unsigned short*)carve((size_t)128 * 256 * 2);
    float* wspool = (float*)carve((size_t)NBX * 2 * 256 * 4);
    int* wsgid = (int*)carve((size_t)NBX * 2 * 4);
    // csr aliases stg1: stg1 is dead after k_scatter2 completes, and k_build
    // (same stream) is the first writer of csr.
    int* csr = (int*)stg1;

    float* pooled = (float*)d_out;
    float* x3 = (float*)d_out + (size_t)G * 256;

    hipMemsetAsync(cnts, 0, (size_t)(64 + NPART) * 4, stream);
    hipMemsetAsync(pooled, 0, (size_t)G * 256 * 4, stream);

    // CSR build: two-level LDS-ranked scatter + meta + partition sort
    k_scatter1<<<(E + 2047) / 2048, 256, 0, stream>>>(src, dst, bcnt1, stg1, E, NB1);
    k_scatter2<<<NB1 * SPLIT, 256, 0, stream>>>(bcnt1, stg1, pcnt, pstg);
    k_meta<<<2, 256, 0, stream>>>(pcnt, pbase, off, batch, gstart, NPART, N, G);
    k_build<<<NPART, 256, 0, stream>>>(pcnt, pstg, pbase, off, csr, N);
    k_prepw_all<<<(98304 + 255) / 256, 256, 0, stream>>>(L1[0], L1[2], L2[0], L2[2],
                                                         Wlt1, Wrt1, Wlt2, Wrt2);

    // layer 0: din=7 -> 128 (fp32 vector, bf16 out)
    k_agg7<<<(N * 8 + 255) / 256, 256, 0, stream>>>(x, off, csr, mean7, N);
    k_layer0<<<(N + 1) / 2, 256, 0, stream>>>(x, mean7, L0[0], L0[1], L0[2], L0[3],
                                              L0[4], L0[5], L0[6], x1, N);

    // layer 1: 128 -> 128, MFMA, in-place on x1 (full-width blocks own their rows)
    k_agg128<<<((size_t)N * 16 + 255) / 256, 256, 0, stream>>>(x1, off, csr, meanb, N);
    k_mfma_layer<128, 128, true><<<dim3(NBX, 1), 256, 0, stream>>>(
        x1, meanb, Wlt1, Wrt1, L1[1], L1[3], L1[4], L1[5], L1[6], x1,
        nullptr, nullptr, nullptr, nullptr, nullptr, N);

    // layer 2: 128 -> 256, MFMA, fp32 out + atomic-free partial pool
    k_agg128<<<((size_t)N * 16 + 255) / 256, 256, 0, stream>>>(x1, off, csr, meanb, N);
    k_mfma_layer<128, 256, false><<<dim3(NBX, 2), 256, 0, stream>>>(
        x1, meanb, Wlt2, Wrt2, L2[1], L2[3], L2[4], L2[5], L2[6], x3,
        batch, gstart, wsgid, wspool, pooled, N);

    // pool reduction: 64 graphs x 256 cols, ~26 blocks each
    k_poolred<<<G, 256, 0, stream>>>(wspool, wsgid, gstart, pooled);
}

// Round 7
// 477.614 us; speedup vs baseline: 1.0444x; 1.0392x over previous
//
#include <hip/hip_runtime.h>
#include <hip/hip_bf16.h>

#define EPSV 1e-5f
#define PSHIFT 6            // partition = 64 nodes
#define PMASK 63
#define PCAP 1536           // per-partition staging cap (mean 1024, +16 sigma)
#define B1SHIFT 11          // coarse bucket = 2048 nodes = 32 partitions
#define B1MASK ((1 << B1SHIFT) - 1)
#define B1CAP 34816         // per-bucket cap (mean 32768, +11 sigma)
#define SPLIT 16            // scatter2 blocks per coarse bucket

typedef __attribute__((ext_vector_type(8))) short bf16x8;
typedef __attribute__((ext_vector_type(4))) float f32x4;
typedef __attribute__((ext_vector_type(4))) unsigned u32x4;

__device__ __forceinline__ float bf2f(unsigned short u) {
    unsigned x = ((unsigned)u) << 16;
    return __builtin_bit_cast(float, x);
}
__device__ __forceinline__ unsigned short f2bf(float f) {
    unsigned x = __builtin_bit_cast(unsigned, f);
    unsigned r = (x + 0x7fffu + ((x >> 16) & 1u)) >> 16;  // RNE
    return (unsigned short)r;
}
__device__ __forceinline__ float u32lo(unsigned v) {
    return __builtin_bit_cast(float, v << 16);
}
__device__ __forceinline__ float u32hi(unsigned v) {
    return __builtin_bit_cast(float, v & 0xffff0000u);
}
__device__ __forceinline__ f32x4 bflo4(u32x4 v) {
    f32x4 r;
    r.x = __builtin_bit_cast(float, v.x << 16);
    r.y = __builtin_bit_cast(float, v.y << 16);
    r.z = __builtin_bit_cast(float, v.z << 16);
    r.w = __builtin_bit_cast(float, v.w << 16);
    return r;
}
__device__ __forceinline__ f32x4 bfhi4(u32x4 v) {
    f32x4 r;
    r.x = __builtin_bit_cast(float, v.x & 0xffff0000u);
    r.y = __builtin_bit_cast(float, v.y & 0xffff0000u);
    r.z = __builtin_bit_cast(float, v.z & 0xffff0000u);
    r.w = __builtin_bit_cast(float, v.w & 0xffff0000u);
    return r;
}

// ---------------- two-level LDS-ranked scatter (R8, verified -42us) ----------------

__global__ __launch_bounds__(256) void k_scatter1(const int* __restrict__ src,
                                                  const int* __restrict__ dst,
                                                  int* __restrict__ bcnt1,
                                                  unsigned* __restrict__ stg1,
                                                  int E, int NB1) {
    __shared__ int hist[64], sbase[64], scur[64];
    int t = threadIdx.x;
    int base = blockIdx.x * 2048;
    if (t < 64) { hist[t] = 0; scur[t] = 0; }
    __syncthreads();
    unsigned val[8];
    int cb[8];
#pragma unroll
    for (int k = 0; k < 8; k++) {
        int i = base + k * 256 + t;
        if (i < E) {
            int d = __builtin_nontemporal_load(&dst[i]);
            int s = __builtin_nontemporal_load(&src[i]);
            cb[k] = d >> B1SHIFT;
            val[k] = ((unsigned)s << B1SHIFT) | (unsigned)(d & B1MASK);
            atomicAdd(&hist[cb[k]], 1);
        } else
            cb[k] = -1;
    }
    __syncthreads();
    if (t < NB1 && hist[t] > 0) sbase[t] = atomicAdd(&bcnt1[t], hist[t]);
    __syncthreads();
#pragma unroll
    for (int k = 0; k < 8; k++) {
        if (cb[k] >= 0) {
            int r = atomicAdd(&scur[cb[k]], 1);
            int slot = sbase[cb[k]] + r;
            if (slot < B1CAP) stg1[(size_t)cb[k] * B1CAP + slot] = val[k];
        }
    }
}

__global__ __launch_bounds__(256) void k_scatter2(const int* __restrict__ bcnt1,
                                                  const unsigned* __restrict__ stg1,
                                                  int* __restrict__ pcnt,
                                                  unsigned* __restrict__ pstg) {
    __shared__ int hist[32], sbase[32], scur[32];
    int cb = blockIdx.x >> 4;  // / SPLIT
    int sl = blockIdx.x & (SPLIT - 1);
    int t = threadIdx.x;
    if (t < 32) { hist[t] = 0; scur[t] = 0; }
    int cnt = min(bcnt1[cb], B1CAP);
    int per = (cnt + SPLIT - 1) / SPLIT;
    int lo = sl * per, hi = min(lo + per, cnt);
    __syncthreads();
    const unsigned* sp = stg1 + (size_t)cb * B1CAP;
    for (int j = lo + t; j < hi; j += 256)
        atomicAdd(&hist[(sp[j] >> 6) & 31], 1);
    __syncthreads();
    if (t < 32 && hist[t] > 0) sbase[t] = atomicAdd(&pcnt[(cb << 5) + t], hist[t]);
    __syncthreads();
    for (int j = lo + t; j < hi; j += 256) {
        unsigned v = sp[j];
        int pr = (v >> 6) & 31;
        int r = atomicAdd(&scur[pr], 1);
        int slot = sbase[pr] + r;
        if (slot < PCAP)
            pstg[(size_t)((cb << 5) + pr) * PCAP + slot] =
                ((v >> 5) & ~63u) | (v & 63u);  // (s<<6)|(d&63)
    }
}

__global__ __launch_bounds__(256) void k_meta(const int* __restrict__ pcnt,
                                              int* __restrict__ pbase,
                                              int* __restrict__ off,
                                              const int* __restrict__ batch,
                                              int* __restrict__ gstart,
                                              int NPART, int Nn, int G) {
    if (blockIdx.x == 1) {
        int g = threadIdx.x;
        if (g > G) return;
        if (g == G) {
            gstart[G] = Nn;
            return;
        }
        int lo = 0, hi = Nn;
        while (lo < hi) {
            int mid = (lo + hi) >> 1;
            if (batch[mid] < g) lo = mid + 1;
            else hi = mid;
        }
        gstart[g] = lo;
        return;
    }
    __shared__ int red[256];
    int t = threadIdx.x;
    int chunk = (NPART + 255) / 256;
    int lo = t * chunk, hi = min(lo + chunk, NPART);
    int s = 0;
    for (int p = lo; p < hi; p++) {
        int tt = min(pcnt[p], PCAP);
        pbase[p] = tt;  // temp: totals
        s += tt;
    }
    red[t] = s;
    __syncthreads();
    for (int d = 1; d < 256; d <<= 1) {
        int v = (t >= d) ? red[t - d] : 0;
        __syncthreads();
        red[t] += v;
        __syncthreads();
    }
    int base = (t == 0) ? 0 : red[t - 1];
    for (int p = lo; p < hi; p++) {
        int tt = pbase[p];
        pbase[p] = base;
        base += tt;
    }
    if (t == 255) off[Nn] = red[255];
}

__global__ __launch_bounds__(256) void k_build(const int* __restrict__ pcnt,
                                               const unsigned* __restrict__ pstg,
                                               const int* __restrict__ pbase,
                                               int* __restrict__ off,
                                               int* __restrict__ csr, int Nn) {
    __shared__ unsigned ed[PCAP];
    __shared__ int srt[PCAP];
    __shared__ int cnt[64], loff[64], cur[64];
    int p = blockIdx.x, t = threadIdx.x;
    int tot = min(pcnt[p], PCAP);
    if (t < 64) cnt[t] = 0;
    __syncthreads();
    const unsigned* sp = pstg + (size_t)p * PCAP;
    for (int j = t; j < tot; j += 256) {
        unsigned e = __builtin_nontemporal_load(&sp[j]);
        ed[j] = e;
        atomicAdd(&cnt[e & PMASK], 1);
    }
    __syncthreads();
    if (t == 0) {
        int a = 0;
        for (int j = 0; j < 64; j++) {
            loff[j] = a;
            cur[j] = a;
            a += cnt[j];
        }
    }
    __syncthreads();
    int base = pbase[p];
    int node0 = p << PSHIFT;
    if (t < 64 && node0 + t < Nn) off[node0 + t] = base + loff[t];
    for (int j = t; j < tot; j += 256) {
        unsigned e = ed[j];
        int pos = atomicAdd(&cur[e & PMASK], 1);
        srt[pos] = (int)(e >> PSHIFT);
    }
    __syncthreads();
    for (int j = t; j < tot; j += 256) csr[base + j] = srt[j];
}

// ---------------- input pack: x [N,7] fp32 -> x7b [N,8] bf16 (1.6 MB) ----------------
// R14: makes the layer-0 gather L2-RESIDENT (1.6 MB < 4 MB per-XCD L2).

__global__ __launch_bounds__(256) void k_prepx(const float* __restrict__ x,
                                               unsigned short* __restrict__ x7b,
                                               int n) {
    int u = blockIdx.x * 256 + threadIdx.x;
    if (u >= n * 8) return;
    int node = u >> 3, f = u & 7;
    float v = (f < 7) ? x[(size_t)node * 7 + f] : 0.f;
    x7b[u] = f2bf(v);
}

// ---------------- layer-0 aggregation (din=7, L2-resident bf16 gather) ----------------
// 4 lanes/node, 1 u32 (2 bf16 feats) per lane per neighbor = coalesced 16B/row.
// mean7 padded to stride 8 for aligned float2 stores.

__global__ __launch_bounds__(256) void k_agg7(const unsigned* __restrict__ x7b,
                                              const int* __restrict__ off,
                                              const int* __restrict__ csr,
                                              float* __restrict__ mean, int n) {
    int i = (blockIdx.x * 256 + threadIdx.x) >> 2;
    int r = threadIdx.x & 3;
    if (i >= n) return;
    int a = off[i], b = off[i + 1];
    float a0 = 0.f, a1 = 0.f;
    int j = a;
    for (; j + 3 < b; j += 4) {
        unsigned v0 = x7b[(size_t)csr[j] * 4 + r];
        unsigned v1 = x7b[(size_t)csr[j + 1] * 4 + r];
        unsigned v2 = x7b[(size_t)csr[j + 2] * 4 + r];
        unsigned v3 = x7b[(size_t)csr[j + 3] * 4 + r];
        a0 += u32lo(v0) + u32lo(v1) + u32lo(v2) + u32lo(v3);
        a1 += u32hi(v0) + u32hi(v1) + u32hi(v2) + u32hi(v3);
    }
    for (; j < b; j++) {
        unsigned v = x7b[(size_t)csr[j] * 4 + r];
        a0 += u32lo(v);
        a1 += u32hi(v);
    }
    float inv = 1.0f / (float)max(b - a, 1);
    *(float2*)&mean[(size_t)i * 8 + r * 2] = make_float2(a0 * inv, a1 * inv);
}

// R13 = R9's best-measured gather (60.6us): 16 lanes/node, 16B loads, 4-deep,
// plain csr loads, plain cacheable store.
__global__ __launch_bounds__(256) void k_agg128(const unsigned short* __restrict__ x,
                                                const int* __restrict__ off,
                                                const int* __restrict__ csr,
                                                unsigned short* __restrict__ mean,
                                                int n) {
    int q = (blockIdx.x * 256 + threadIdx.x) >> 4;  // quarter-wave = node
    int sl = threadIdx.x & 15;
    if (q >= n) return;
    int a = off[q], b = off[q + 1];
    const u32x4* xr = (const u32x4*)x;  // 16 x 16B per 128-col row
    f32x4 aL = {0.f, 0.f, 0.f, 0.f}, aH = {0.f, 0.f, 0.f, 0.f};
    int j = a;
    for (; j + 3 < b; j += 4) {
        int s0 = csr[j], s1 = csr[j + 1], s2 = csr[j + 2], s3 = csr[j + 3];
        u32x4 v0 = xr[(size_t)s0 * 16 + sl];
        u32x4 v1 = xr[(size_t)s1 * 16 + sl];
        u32x4 v2 = xr[(size_t)s2 * 16 + sl];
        u32x4 v3 = xr[(size_t)s3 * 16 + sl];
        aL += bflo4(v0) + bflo4(v1) + bflo4(v2) + bflo4(v3);
        aH += bfhi4(v0) + bfhi4(v1) + bfhi4(v2) + bfhi4(v3);
    }
    for (; j < b; j++) {
        u32x4 v = xr[(size_t)csr[j] * 16 + sl];
        aL += bflo4(v);
        aH += bfhi4(v);
    }
    float inv = 1.0f / (float)max(b - a, 1);
    u32x4 o;
    o.x = (unsigned)f2bf(aL.x * inv) | ((unsigned)f2bf(aH.x * inv) << 16);
    o.y = (unsigned)f2bf(aL.y * inv) | ((unsigned)f2bf(aH.y * inv) << 16);
    o.z = (unsigned)f2bf(aL.z * inv) | ((unsigned)f2bf(aH.z * inv) << 16);
    o.w = (unsigned)f2bf(aL.w * inv) | ((unsigned)f2bf(aH.w * inv) << 16);
    *((u32x4*)mean + (size_t)q * 16 + sl) = o;
}

// ---------------- weight prep ----------------

__global__ __launch_bounds__(256) void k_prepw_all(
    const float* __restrict__ Wl1, const float* __restrict__ Wr1,
    const float* __restrict__ Wl2, const float* __restrict__ Wr2,
    unsigned short* __restrict__ Wlt1, unsigned short* __restrict__ Wrt1,
    unsigned short* __restrict__ Wlt2, unsigned short* __restrict__ Wrt2) {
    int u = blockIdx.x * 256 + threadIdx.x;
    const float* W;
    unsigned short* Wt;
    int Ncols, v;
    if (u < 32768) {
        v = u & 16383;
        W = (u < 16384) ? Wl1 : Wr1;
        Wt = (u < 16384) ? Wlt1 : Wrt1;
        Ncols = 128;
    } else {
        v = (u - 32768) & 32767;
        W = (u < 65536) ? Wl2 : Wr2;
        Wt = (u < 65536) ? Wlt2 : Wrt2;
        Ncols = 256;
    }
    int n = v % Ncols, k = v / Ncols;
    Wt[(size_t)n * 128 + k] = f2bf(W[(size_t)k * Ncols + n]);
}

// ---------------- layer 0 (din=7, fp32 vector) -> bf16 out ----------------
// mean7 stride is 8 (padded).

__global__ __launch_bounds__(256) void k_layer0(
    const float* __restrict__ x, const float* __restrict__ mean,
    const float* __restrict__ Wl, const float* __restrict__ bl,
    const float* __restrict__ Wr, const float* __restrict__ g,
    const float* __restrict__ be, const float* __restrict__ rm,
    const float* __restrict__ rv, unsigned short* __restrict__ out, int n) {
    int tid = threadIdx.x;
    int col = tid & 127;
    int r = tid >> 7;
    int row = blockIdx.x * 2 + r;
    if (row >= n) return;
    float sc = g[col] * rsqrtf(rv[col] + EPSV);
    float sh = (bl[col] - rm[col]) * sc + be[col];
    const float* xp = x + (size_t)row * 7;
    const float* mp = mean + (size_t)row * 8;
    float acc = 0.f;
#pragma unroll
    for (int k = 0; k < 7; k++) acc += xp[k] * Wl[k * 128 + col];
#pragma unroll
    for (int k = 0; k < 7; k++) acc += mp[k] * Wr[k * 128 + col];
    float h = acc * sc + sh;
    out[(size_t)row * 128 + col] = f2bf(fmaxf(h, 0.f));
}

// ---------------- MFMA layer (pure R11 core -- measured best) ----------------
// Pool fusion attempted 3x (R2/R3/R6), regressed every time; pooling stays in
// k_pool. 64 rows x COLS(=128) per block, simple 8-stage loop.

template <int COLS, int DOUT, bool BF16OUT>
__global__ __launch_bounds__(256) void k_mfma_layer(
    const unsigned short* __restrict__ xin, const unsigned short* __restrict__ meanb,
    const unsigned short* __restrict__ Wlt, const unsigned short* __restrict__ Wrt,
    const float* __restrict__ bl, const float* __restrict__ g,
    const float* __restrict__ be, const float* __restrict__ rm,
    const float* __restrict__ rv, void* __restrict__ outv, int n) {
    __shared__ unsigned short As[64 * 40];
    __shared__ unsigned short Bs[COLS * 40];

    int tid = threadIdx.x;
    int wave = tid >> 6;
    int lane = tid & 63;
    int m = lane & 15;
    int half = lane >> 4;
    int row0 = blockIdx.x * 64;
    int colbase = blockIdx.y * COLS;

    const int NCB = COLS / 16;
    f32x4 acc[NCB] = {};

    for (int s = 0; s < 8; s++) {
        int pass = s >> 2;
        int k0 = (s & 3) * 32;
        const unsigned short* Asrc = pass ? meanb : xin;
        const unsigned short* Wt = pass ? Wrt : Wlt;

        __syncthreads();
        {   // stage A: 64 rows x 32 k
            int rr = tid >> 2;
            int ks = (tid & 3) * 8;
            int grow = row0 + rr;
            float4 v = make_float4(0.f, 0.f, 0.f, 0.f);
            if (grow < n) v = *(const float4*)&Asrc[(size_t)grow * 128 + k0 + ks];
            *(float4*)&As[rr * 40 + ks] = v;
        }
#pragma unroll
        for (int rep = 0; rep < COLS / 64; rep++) {  // stage B: COLS cols x 32 k
            int u = tid + rep * 256;
            int nn = u >> 2;
            int ks = (u & 3) * 8;
            float4 v = *(const float4*)&Wt[(size_t)(colbase + nn) * 128 + k0 + ks];
            *(float4*)&Bs[nn * 40 + ks] = v;
        }
        __syncthreads();

        bf16x8 a = *(const bf16x8*)&As[(wave * 16 + m) * 40 + half * 8];
#pragma unroll
        for (int cb = 0; cb < NCB; cb++) {
            bf16x8 b = *(const bf16x8*)&Bs[(cb * 16 + m) * 40 + half * 8];
            acc[cb] = __builtin_amdgcn_mfma_f32_16x16x32_bf16(a, b, acc[cb], 0, 0, 0);
        }
    }

    float* outf = (float*)outv;
    unsigned short* outb = (unsigned short*)outv;
#pragma unroll
    for (int cb = 0; cb < NCB; cb++) {
        int col = colbase + cb * 16 + m;
        float sc = g[col] * rsqrtf(rv[col] + EPSV);
        float sh = (bl[col] - rm[col]) * sc + be[col];
#pragma unroll
        for (int reg = 0; reg < 4; reg++) {
            int r0 = row0 + wave * 16 + half * 4 + reg;
            if (r0 < n) {
                float h = fmaxf(acc[cb][reg] * sc + sh, 0.f);
                if (BF16OUT) outb[(size_t)r0 * DOUT + col] = f2bf(h);
                else outf[(size_t)r0 * DOUT + col] = h;
            }
        }
    }
}

// ---------------- pooling ----------------

__global__ __launch_bounds__(256) void k_pool(const float* __restrict__ x3,
                                              const int* __restrict__ gstart,
                                              float* __restrict__ pooled, int G) {
    const int S = 16;
    int g = blockIdx.x / S;
    int s = blockIdx.x % S;
    int a = gstart[g], b = gstart[g + 1];
    int col = threadIdx.x;
    float acc = 0.f;
    for (int r = a + s; r < b; r += S) acc += x3[(size_t)r * 256 + col];
    atomicAdd(&pooled[g * 256 + col], acc);
}

// ---------------- launch ----------------

extern "C" void kernel_launch(void* const* d_in, const int* in_sizes, int n_in,
                              void* d_out, int out_size, void* d_ws, size_t ws_size,
                              hipStream_t stream) {
    const float* x = (const float*)d_in[0];
    const int* ei = (const int*)d_in[1];
    const int* batch = (const int*)d_in[2];
    const int N = in_sizes[0] / 7;
    const int E = in_sizes[1] / 2;
    const int G = 64;
    const int* src = ei;
    const int* dst = ei + E;
    const int NPART = (N + PMASK) >> PSHIFT;
    const int NB1 = (N + (1 << B1SHIFT) - 1) >> B1SHIFT;
    const int NBX = (N + 63) / 64;

    const float* P[21];
    for (int i = 0; i < 21; i++) P[i] = (const float*)d_in[3 + i];
    const float **L0 = P, **L1 = P + 7, **L2 = P + 14;

    char* w = (char*)d_ws;
    auto carve = [&](size_t bytes) {
        void* p = (void*)w;
        w += (bytes + 255) & ~(size_t)255;
        return p;
    };
    int* cnts = (int*)carve((size_t)(64 + NPART) * 4);  // bcnt1[64] + pcnt[NPART]
    int* bcnt1 = cnts;
    int* pcnt = cnts + 64;
    unsigned* stg1 = (unsigned*)carve((size_t)NB1 * B1CAP * 4);
    unsigned* pstg = (unsigned*)carve((size_t)NPART * PCAP * 4);
    int* pbase = (int*)carve((size_t)NPART * 4);
    int* off = (int*)carve(((size_t)N + 1) * 4);
    int* gstart = (int*)carve(((size_t)G + 1) * 4);
    unsigned short* x7b = (unsigned short*)carve((size_t)N * 8 * 2);
    float* mean7 = (float*)carve((size_t)N * 8 * 4);
    unsigned short* x1 = (unsigned short*)carve((size_t)N * 128 * 2);
    unsigned short* meanb = (unsigned short*)carve((size_t)N * 128 * 2);
    unsigned short* Wlt1 = (unsigned short*)carve((size_t)128 * 128 * 2);
    unsigned short* Wrt1 = (unsigned short*)carve((size_t)128 * 128 * 2);
    unsigned short* Wlt2 = (unsigned short*)carve((size_t)128 * 256 * 2);
    unsigned short* Wrt2 = (unsigned short*)carve((size_t)128 * 256 * 2);
    // csr aliases stg1: stg1 is dead after k_scatter2 completes, and k_build
    // (same stream) is the first writer of csr.
    int* csr = (int*)stg1;

    float* pooled = (float*)d_out;
    float* x3 = (float*)d_out + (size_t)G * 256;

    hipMemsetAsync(cnts, 0, (size_t)(64 + NPART) * 4, stream);
    hipMemsetAsync(pooled, 0, (size_t)G * 256 * 4, stream);

    // CSR build: two-level LDS-ranked scatter + meta + partition sort
    k_scatter1<<<(E + 2047) / 2048, 256, 0, stream>>>(src, dst, bcnt1, stg1, E, NB1);
    k_scatter2<<<NB1 * SPLIT, 256, 0, stream>>>(bcnt1, stg1, pcnt, pstg);
    k_meta<<<2, 256, 0, stream>>>(pcnt, pbase, off, batch, gstart, NPART, N, G);
    k_build<<<NPART, 256, 0, stream>>>(pcnt, pstg, pbase, off, csr, N);
    k_prepx<<<(N * 8 + 255) / 256, 256, 0, stream>>>(x, x7b, N);
    k_prepw_all<<<(98304 + 255) / 256, 256, 0, stream>>>(L1[0], L1[2], L2[0], L2[2],
                                                         Wlt1, Wrt1, Wlt2, Wrt2);

    // layer 0: din=7 -> 128 (L2-resident bf16 gather + fp32 vector GEMM)
    k_agg7<<<((size_t)N * 4 + 255) / 256, 256, 0, stream>>>((const unsigned*)x7b,
                                                            off, csr, mean7, N);
    k_layer0<<<(N + 1) / 2, 256, 0, stream>>>(x, mean7, L0[0], L0[1], L0[2], L0[3],
                                              L0[4], L0[5], L0[6], x1, N);

    // layer 1: 128 -> 128, MFMA, in-place on x1 (full-width blocks own their rows)
    k_agg128<<<((size_t)N * 16 + 255) / 256, 256, 0, stream>>>(x1, off, csr, meanb, N);
    k_mfma_layer<128, 128, true><<<dim3(NBX, 1), 256, 0, stream>>>(
        x1, meanb, Wlt1, Wrt1, L1[1], L1[3], L1[4], L1[5], L1[6], x1, N);

    // layer 2: 128 -> 256, MFMA, fp32 out into d_out x-region
    k_agg128<<<((size_t)N * 16 + 255) / 256, 256, 0, stream>>>(x1, off, csr, meanb, N);
    k_mfma_layer<128, 256, false><<<dim3(NBX, 2), 256, 0, stream>>>(
        x1, meanb, Wlt2, Wrt2, L2[1], L2[3], L2[4], L2[5], L2[6], x3, N);

    // global add pool
    k_pool<<<G * 16, 256, 0, stream>>>(x3, gstart, pooled, G);
}

// Round 8
// 437.135 us; speedup vs baseline: 1.1411x; 1.0926x over previous
//
#include <hip/hip_runtime.h>
#include <hip/hip_bf16.h>

#define EPSV 1e-5f
#define PSHIFT 6            // partition = 64 nodes
#define PMASK 63
#define PCAP 1536           // per-partition staging cap (mean 1024, +16 sigma)
#define B1SHIFT 11          // coarse bucket = 2048 nodes = 32 partitions
#define B1MASK ((1 << B1SHIFT) - 1)
#define B1CAP 34816         // per-bucket cap (mean 32768, +11 sigma)
#define SPLIT 16            // scatter2 blocks per coarse bucket

typedef __attribute__((ext_vector_type(8))) short bf16x8;
typedef __attribute__((ext_vector_type(4))) float f32x4;
typedef __attribute__((ext_vector_type(4))) unsigned u32x4;

__device__ __forceinline__ float bf2f(unsigned short u) {
    unsigned x = ((unsigned)u) << 16;
    return __builtin_bit_cast(float, x);
}
__device__ __forceinline__ unsigned short f2bf(float f) {
    unsigned x = __builtin_bit_cast(unsigned, f);
    unsigned r = (x + 0x7fffu + ((x >> 16) & 1u)) >> 16;  // RNE
    return (unsigned short)r;
}
__device__ __forceinline__ float u32lo(unsigned v) {
    return __builtin_bit_cast(float, v << 16);
}
__device__ __forceinline__ float u32hi(unsigned v) {
    return __builtin_bit_cast(float, v & 0xffff0000u);
}
__device__ __forceinline__ f32x4 bflo4(u32x4 v) {
    f32x4 r;
    r.x = __builtin_bit_cast(float, v.x << 16);
    r.y = __builtin_bit_cast(float, v.y << 16);
    r.z = __builtin_bit_cast(float, v.z << 16);
    r.w = __builtin_bit_cast(float, v.w << 16);
    return r;
}
__device__ __forceinline__ f32x4 bfhi4(u32x4 v) {
    f32x4 r;
    r.x = __builtin_bit_cast(float, v.x & 0xffff0000u);
    r.y = __builtin_bit_cast(float, v.y & 0xffff0000u);
    r.z = __builtin_bit_cast(float, v.z & 0xffff0000u);
    r.w = __builtin_bit_cast(float, v.w & 0xffff0000u);
    return r;
}

// ---------------- two-level LDS-ranked scatter (R8, verified -42us) ----------------

__global__ __launch_bounds__(256) void k_scatter1(const int* __restrict__ src,
                                                  const int* __restrict__ dst,
                                                  int* __restrict__ bcnt1,
                                                  unsigned* __restrict__ stg1,
                                                  int E, int NB1) {
    __shared__ int hist[64], sbase[64], scur[64];
    int t = threadIdx.x;
    int base = blockIdx.x * 2048;
    if (t < 64) { hist[t] = 0; scur[t] = 0; }
    __syncthreads();
    unsigned val[8];
    int cb[8];
#pragma unroll
    for (int k = 0; k < 8; k++) {
        int i = base + k * 256 + t;
        if (i < E) {
            int d = __builtin_nontemporal_load(&dst[i]);
            int s = __builtin_nontemporal_load(&src[i]);
            cb[k] = d >> B1SHIFT;
            val[k] = ((unsigned)s << B1SHIFT) | (unsigned)(d & B1MASK);
            atomicAdd(&hist[cb[k]], 1);
        } else
            cb[k] = -1;
    }
    __syncthreads();
    if (t < NB1 && hist[t] > 0) sbase[t] = atomicAdd(&bcnt1[t], hist[t]);
    __syncthreads();
#pragma unroll
    for (int k = 0; k < 8; k++) {
        if (cb[k] >= 0) {
            int r = atomicAdd(&scur[cb[k]], 1);
            int slot = sbase[cb[k]] + r;
            if (slot < B1CAP) stg1[(size_t)cb[k] * B1CAP + slot] = val[k];
        }
    }
}

__global__ __launch_bounds__(256) void k_scatter2(const int* __restrict__ bcnt1,
                                                  const unsigned* __restrict__ stg1,
                                                  int* __restrict__ pcnt,
                                                  unsigned* __restrict__ pstg) {
    __shared__ int hist[32], sbase[32], scur[32];
    int cb = blockIdx.x >> 4;  // / SPLIT
    int sl = blockIdx.x & (SPLIT - 1);
    int t = threadIdx.x;
    if (t < 32) { hist[t] = 0; scur[t] = 0; }
    int cnt = min(bcnt1[cb], B1CAP);
    int per = (cnt + SPLIT - 1) / SPLIT;
    int lo = sl * per, hi = min(lo + per, cnt);
    __syncthreads();
    const unsigned* sp = stg1 + (size_t)cb * B1CAP;
    for (int j = lo + t; j < hi; j += 256)
        atomicAdd(&hist[(sp[j] >> 6) & 31], 1);
    __syncthreads();
    if (t < 32 && hist[t] > 0) sbase[t] = atomicAdd(&pcnt[(cb << 5) + t], hist[t]);
    __syncthreads();
    for (int j = lo + t; j < hi; j += 256) {
        unsigned v = sp[j];
        int pr = (v >> 6) & 31;
        int r = atomicAdd(&scur[pr], 1);
        int slot = sbase[pr] + r;
        if (slot < PCAP)
            pstg[(size_t)((cb << 5) + pr) * PCAP + slot] =
                ((v >> 5) & ~63u) | (v & 63u);  // (s<<6)|(d&63)
    }
}

__global__ __launch_bounds__(256) void k_meta(const int* __restrict__ pcnt,
                                              int* __restrict__ pbase,
                                              int* __restrict__ off,
                                              const int* __restrict__ batch,
                                              int* __restrict__ gstart,
                                              int NPART, int Nn, int G) {
    if (blockIdx.x == 1) {
        int g = threadIdx.x;
        if (g > G) return;
        if (g == G) {
            gstart[G] = Nn;
            return;
        }
        int lo = 0, hi = Nn;
        while (lo < hi) {
            int mid = (lo + hi) >> 1;
            if (batch[mid] < g) lo = mid + 1;
            else hi = mid;
        }
        gstart[g] = lo;
        return;
    }
    __shared__ int red[256];
    int t = threadIdx.x;
    int chunk = (NPART + 255) / 256;
    int lo = t * chunk, hi = min(lo + chunk, NPART);
    int s = 0;
    for (int p = lo; p < hi; p++) {
        int tt = min(pcnt[p], PCAP);
        pbase[p] = tt;  // temp: totals
        s += tt;
    }
    red[t] = s;
    __syncthreads();
    for (int d = 1; d < 256; d <<= 1) {
        int v = (t >= d) ? red[t - d] : 0;
        __syncthreads();
        red[t] += v;
        __syncthreads();
    }
    int base = (t == 0) ? 0 : red[t - 1];
    for (int p = lo; p < hi; p++) {
        int tt = pbase[p];
        pbase[p] = base;
        base += tt;
    }
    if (t == 255) off[Nn] = red[255];
}

__global__ __launch_bounds__(256) void k_build(const int* __restrict__ pcnt,
                                               const unsigned* __restrict__ pstg,
                                               const int* __restrict__ pbase,
                                               int* __restrict__ off,
                                               int* __restrict__ csr, int Nn) {
    __shared__ unsigned ed[PCAP];
    __shared__ int srt[PCAP];
    __shared__ int cnt[64], loff[64], cur[64];
    int p = blockIdx.x, t = threadIdx.x;
    int tot = min(pcnt[p], PCAP);
    if (t < 64) cnt[t] = 0;
    __syncthreads();
    const unsigned* sp = pstg + (size_t)p * PCAP;
    for (int j = t; j < tot; j += 256) {
        unsigned e = __builtin_nontemporal_load(&sp[j]);
        ed[j] = e;
        atomicAdd(&cnt[e & PMASK], 1);
    }
    __syncthreads();
    if (t == 0) {
        int a = 0;
        for (int j = 0; j < 64; j++) {
            loff[j] = a;
            cur[j] = a;
            a += cnt[j];
        }
    }
    __syncthreads();
    int base = pbase[p];
    int node0 = p << PSHIFT;
    if (t < 64 && node0 + t < Nn) off[node0 + t] = base + loff[t];
    for (int j = t; j < tot; j += 256) {
        unsigned e = ed[j];
        int pos = atomicAdd(&cur[e & PMASK], 1);
        srt[pos] = (int)(e >> PSHIFT);
    }
    __syncthreads();
    for (int j = t; j < tot; j += 256) csr[base + j] = srt[j];
}

// ---------------- input pack: x [N,7] fp32 -> x7b [N,8] bf16 (1.6 MB) ----------------
// R14 (verified): makes the layer-0 gather L2-RESIDENT (1.6 MB < 4 MB/XCD L2).

__global__ __launch_bounds__(256) void k_prepx(const float* __restrict__ x,
                                               unsigned short* __restrict__ x7b,
                                               int n) {
    int u = blockIdx.x * 256 + threadIdx.x;
    if (u >= n * 8) return;
    int node = u >> 3, f = u & 7;
    float v = (f < 7) ? x[(size_t)node * 7 + f] : 0.f;
    x7b[u] = f2bf(v);
}

// ---------------- layer-0 aggregation (din=7, L2-resident bf16 gather) ----------------

__global__ __launch_bounds__(256) void k_agg7(const unsigned* __restrict__ x7b,
                                              const int* __restrict__ off,
                                              const int* __restrict__ csr,
                                              float* __restrict__ mean, int n) {
    int i = (blockIdx.x * 256 + threadIdx.x) >> 2;
    int r = threadIdx.x & 3;
    if (i >= n) return;
    int a = off[i], b = off[i + 1];
    float a0 = 0.f, a1 = 0.f;
    int j = a;
    for (; j + 3 < b; j += 4) {
        unsigned v0 = x7b[(size_t)csr[j] * 4 + r];
        unsigned v1 = x7b[(size_t)csr[j + 1] * 4 + r];
        unsigned v2 = x7b[(size_t)csr[j + 2] * 4 + r];
        unsigned v3 = x7b[(size_t)csr[j + 3] * 4 + r];
        a0 += u32lo(v0) + u32lo(v1) + u32lo(v2) + u32lo(v3);
        a1 += u32hi(v0) + u32hi(v1) + u32hi(v2) + u32hi(v3);
    }
    for (; j < b; j++) {
        unsigned v = x7b[(size_t)csr[j] * 4 + r];
        a0 += u32lo(v);
        a1 += u32hi(v);
    }
    float inv = 1.0f / (float)max(b - a, 1);
    *(float2*)&mean[(size_t)i * 8 + r * 2] = make_float2(a0 * inv, a1 * inv);
}

// R13 = R9's best-measured gather (60.6us): 16 lanes/node, 16B loads, 4-deep.
__global__ __launch_bounds__(256) void k_agg128(const unsigned short* __restrict__ x,
                                                const int* __restrict__ off,
                                                const int* __restrict__ csr,
                                                unsigned short* __restrict__ mean,
                                                int n) {
    int q = (blockIdx.x * 256 + threadIdx.x) >> 4;  // quarter-wave = node
    int sl = threadIdx.x & 15;
    if (q >= n) return;
    int a = off[q], b = off[q + 1];
    const u32x4* xr = (const u32x4*)x;  // 16 x 16B per 128-col row
    f32x4 aL = {0.f, 0.f, 0.f, 0.f}, aH = {0.f, 0.f, 0.f, 0.f};
    int j = a;
    for (; j + 3 < b; j += 4) {
        int s0 = csr[j], s1 = csr[j + 1], s2 = csr[j + 2], s3 = csr[j + 3];
        u32x4 v0 = xr[(size_t)s0 * 16 + sl];
        u32x4 v1 = xr[(size_t)s1 * 16 + sl];
        u32x4 v2 = xr[(size_t)s2 * 16 + sl];
        u32x4 v3 = xr[(size_t)s3 * 16 + sl];
        aL += bflo4(v0) + bflo4(v1) + bflo4(v2) + bflo4(v3);
        aH += bfhi4(v0) + bfhi4(v1) + bfhi4(v2) + bfhi4(v3);
    }
    for (; j < b; j++) {
        u32x4 v = xr[(size_t)csr[j] * 16 + sl];
        aL += bflo4(v);
        aH += bfhi4(v);
    }
    float inv = 1.0f / (float)max(b - a, 1);
    u32x4 o;
    o.x = (unsigned)f2bf(aL.x * inv) | ((unsigned)f2bf(aH.x * inv) << 16);
    o.y = (unsigned)f2bf(aL.y * inv) | ((unsigned)f2bf(aH.y * inv) << 16);
    o.z = (unsigned)f2bf(aL.z * inv) | ((unsigned)f2bf(aH.z * inv) << 16);
    o.w = (unsigned)f2bf(aL.w * inv) | ((unsigned)f2bf(aH.w * inv) << 16);
    *((u32x4*)mean + (size_t)q * 16 + sl) = o;
}

// ---------------- weight prep ----------------

__global__ __launch_bounds__(256) void k_prepw_all(
    const float* __restrict__ Wl1, const float* __restrict__ Wr1,
    const float* __restrict__ Wl2, const float* __restrict__ Wr2,
    unsigned short* __restrict__ Wlt1, unsigned short* __restrict__ Wrt1,
    unsigned short* __restrict__ Wlt2, unsigned short* __restrict__ Wrt2) {
    int u = blockIdx.x * 256 + threadIdx.x;
    const float* W;
    unsigned short* Wt;
    int Ncols, v;
    if (u < 32768) {
        v = u & 16383;
        W = (u < 16384) ? Wl1 : Wr1;
        Wt = (u < 16384) ? Wlt1 : Wrt1;
        Ncols = 128;
    } else {
        v = (u - 32768) & 32767;
        W = (u < 65536) ? Wl2 : Wr2;
        Wt = (u < 65536) ? Wlt2 : Wrt2;
        Ncols = 256;
    }
    int n = v % Ncols, k = v / Ncols;
    Wt[(size_t)n * 128 + k] = f2bf(W[(size_t)k * Ncols + n]);
}

// ---------------- layer 0 (din=7) -> bf16 out ----------------
// R15: 32 rows/block. Weights + BN affine hoisted to registers (14 loads
// once per thread, not per element); x/mean rows staged cooperatively into
// 2KB LDS; inner loop = pure register FMA + LDS broadcast reads. Old version
// was 60us of raw load latency (28 dependent scalar loads per 14-FMA thread).

__global__ __launch_bounds__(256) void k_layer0(
    const float* __restrict__ x, const float* __restrict__ mean,
    const float* __restrict__ Wl, const float* __restrict__ bl,
    const float* __restrict__ Wr, const float* __restrict__ g,
    const float* __restrict__ be, const float* __restrict__ rm,
    const float* __restrict__ rv, unsigned short* __restrict__ out, int n) {
    __shared__ float xs[32][8];
    __shared__ float ms[32][8];
    int tid = threadIdx.x;
    int col = tid & 127;
    int hr = tid >> 7;  // 0: rows 0-15, 1: rows 16-31
    int row0 = blockIdx.x * 32;

    float wl[7], wr[7];
#pragma unroll
    for (int k = 0; k < 7; k++) {
        wl[k] = Wl[k * 128 + col];
        wr[k] = Wr[k * 128 + col];
    }
    float sc = g[col] * rsqrtf(rv[col] + EPSV);
    float sh = (bl[col] - rm[col]) * sc + be[col];

    if (tid < 224) {  // 32 rows x 7 feats
        int r = tid / 7, f = tid % 7;
        int gr = row0 + r;
        xs[r][f] = (gr < n) ? x[(size_t)gr * 7 + f] : 0.f;
    }
    {   // 32 rows x 8 feats (mean7 stride 8)
        int r = tid >> 3, f = tid & 7;
        int gr = row0 + r;
        ms[r][f] = (gr < n) ? mean[(size_t)gr * 8 + f] : 0.f;
    }
    __syncthreads();

#pragma unroll
    for (int rr = 0; rr < 16; rr++) {
        int r = hr * 16 + rr;
        int grow = row0 + r;
        if (grow >= n) break;
        float acc = 0.f;
#pragma unroll
        for (int k = 0; k < 7; k++) acc = fmaf(xs[r][k], wl[k], acc);
#pragma unroll
        for (int k = 0; k < 7; k++) acc = fmaf(ms[r][k], wr[k], acc);
        float h = acc * sc + sh;
        out[(size_t)grow * 128 + col] = f2bf(fmaxf(h, 0.f));
    }
}

// ---------------- MFMA layer (pure R11 core -- measured best) ----------------
// Pool fusion attempted 3x (R2/R3/R6), regressed every time; pooling stays in
// k_pool. 64 rows x COLS(=128) per block, simple 8-stage loop.

template <int COLS, int DOUT, bool BF16OUT>
__global__ __launch_bounds__(256) void k_mfma_layer(
    const unsigned short* __restrict__ xin, const unsigned short* __restrict__ meanb,
    const unsigned short* __restrict__ Wlt, const unsigned short* __restrict__ Wrt,
    const float* __restrict__ bl, const float* __restrict__ g,
    const float* __restrict__ be, const float* __restrict__ rm,
    const float* __restrict__ rv, void* __restrict__ outv, int n) {
    __shared__ unsigned short As[64 * 40];
    __shared__ unsigned short Bs[COLS * 40];

    int tid = threadIdx.x;
    int wave = tid >> 6;
    int lane = tid & 63;
    int m = lane & 15;
    int half = lane >> 4;
    int row0 = blockIdx.x * 64;
    int colbase = blockIdx.y * COLS;

    const int NCB = COLS / 16;
    f32x4 acc[NCB] = {};

    for (int s = 0; s < 8; s++) {
        int pass = s >> 2;
        int k0 = (s & 3) * 32;
        const unsigned short* Asrc = pass ? meanb : xin;
        const unsigned short* Wt = pass ? Wrt : Wlt;

        __syncthreads();
        {   // stage A: 64 rows x 32 k
            int rr = tid >> 2;
            int ks = (tid & 3) * 8;
            int grow = row0 + rr;
            float4 v = make_float4(0.f, 0.f, 0.f, 0.f);
            if (grow < n) v = *(const float4*)&Asrc[(size_t)grow * 128 + k0 + ks];
            *(float4*)&As[rr * 40 + ks] = v;
        }
#pragma unroll
        for (int rep = 0; rep < COLS / 64; rep++) {  // stage B: COLS cols x 32 k
            int u = tid + rep * 256;
            int nn = u >> 2;
            int ks = (u & 3) * 8;
            float4 v = *(const float4*)&Wt[(size_t)(colbase + nn) * 128 + k0 + ks];
            *(float4*)&Bs[nn * 40 + ks] = v;
        }
        __syncthreads();

        bf16x8 a = *(const bf16x8*)&As[(wave * 16 + m) * 40 + half * 8];
#pragma unroll
        for (int cb = 0; cb < NCB; cb++) {
            bf16x8 b = *(const bf16x8*)&Bs[(cb * 16 + m) * 40 + half * 8];
            acc[cb] = __builtin_amdgcn_mfma_f32_16x16x32_bf16(a, b, acc[cb], 0, 0, 0);
        }
    }

    float* outf = (float*)outv;
    unsigned short* outb = (unsigned short*)outv;
#pragma unroll
    for (int cb = 0; cb < NCB; cb++) {
        int col = colbase + cb * 16 + m;
        float sc = g[col] * rsqrtf(rv[col] + EPSV);
        float sh = (bl[col] - rm[col]) * sc + be[col];
#pragma unroll
        for (int reg = 0; reg < 4; reg++) {
            int r0 = row0 + wave * 16 + half * 4 + reg;
            if (r0 < n) {
                float h = fmaxf(acc[cb][reg] * sc + sh, 0.f);
                if (BF16OUT) outb[(size_t)r0 * DOUT + col] = f2bf(h);
                else outf[(size_t)r0 * DOUT + col] = h;
            }
        }
    }
}

// ---------------- pooling ----------------

__global__ __launch_bounds__(256) void k_pool(const float* __restrict__ x3,
                                              const int* __restrict__ gstart,
                                              float* __restrict__ pooled, int G) {
    const int S = 16;
    int g = blockIdx.x / S;
    int s = blockIdx.x % S;
    int a = gstart[g], b = gstart[g + 1];
    int col = threadIdx.x;
    float acc = 0.f;
    for (int r = a + s; r < b; r += S) acc += x3[(size_t)r * 256 + col];
    atomicAdd(&pooled[g * 256 + col], acc);
}

// ---------------- launch ----------------

extern "C" void kernel_launch(void* const* d_in, const int* in_sizes, int n_in,
                              void* d_out, int out_size, void* d_ws, size_t ws_size,
                              hipStream_t stream) {
    const float* x = (const float*)d_in[0];
    const int* ei = (const int*)d_in[1];
    const int* batch = (const int*)d_in[2];
    const int N = in_sizes[0] / 7;
    const int E = in_sizes[1] / 2;
    const int G = 64;
    const int* src = ei;
    const int* dst = ei + E;
    const int NPART = (N + PMASK) >> PSHIFT;
    const int NB1 = (N + (1 << B1SHIFT) - 1) >> B1SHIFT;
    const int NBX = (N + 63) / 64;

    const float* P[21];
    for (int i = 0; i < 21; i++) P[i] = (const float*)d_in[3 + i];
    const float **L0 = P, **L1 = P + 7, **L2 = P + 14;

    char* w = (char*)d_ws;
    auto carve = [&](size_t bytes) {
        void* p = (void*)w;
        w += (bytes + 255) & ~(size_t)255;
        return p;
    };
    int* cnts = (int*)carve((size_t)(64 + NPART) * 4);  // bcnt1[64] + pcnt[NPART]
    int* bcnt1 = cnts;
    int* pcnt = cnts + 64;
    unsigned* stg1 = (unsigned*)carve((size_t)NB1 * B1CAP * 4);
    unsigned* pstg = (unsigned*)carve((size_t)NPART * PCAP * 4);
    int* pbase = (int*)carve((size_t)NPART * 4);
    int* off = (int*)carve(((size_t)N + 1) * 4);
    int* gstart = (int*)carve(((size_t)G + 1) * 4);
    unsigned short* x7b = (unsigned short*)carve((size_t)N * 8 * 2);
    float* mean7 = (float*)carve((size_t)N * 8 * 4);
    unsigned short* x1 = (unsigned short*)carve((size_t)N * 128 * 2);
    unsigned short* meanb = (unsigned short*)carve((size_t)N * 128 * 2);
    unsigned short* Wlt1 = (unsigned short*)carve((size_t)128 * 128 * 2);
    unsigned short* Wrt1 = (unsigned short*)carve((size_t)128 * 128 * 2);
    unsigned short* Wlt2 = (unsigned short*)carve((size_t)128 * 256 * 2);
    unsigned short* Wrt2 = (unsigned short*)carve((size_t)128 * 256 * 2);
    // csr aliases stg1: stg1 is dead after k_scatter2 completes, and k_build
    // (same stream) is the first writer of csr.
    int* csr = (int*)stg1;

    float* pooled = (float*)d_out;
    float* x3 = (float*)d_out + (size_t)G * 256;

    hipMemsetAsync(cnts, 0, (size_t)(64 + NPART) * 4, stream);
    hipMemsetAsync(pooled, 0, (size_t)G * 256 * 4, stream);

    // CSR build: two-level LDS-ranked scatter + meta + partition sort
    k_scatter1<<<(E + 2047) / 2048, 256, 0, stream>>>(src, dst, bcnt1, stg1, E, NB1);
    k_scatter2<<<NB1 * SPLIT, 256, 0, stream>>>(bcnt1, stg1, pcnt, pstg);
    k_meta<<<2, 256, 0, stream>>>(pcnt, pbase, off, batch, gstart, NPART, N, G);
    k_build<<<NPART, 256, 0, stream>>>(pcnt, pstg, pbase, off, csr, N);
    k_prepx<<<(N * 8 + 255) / 256, 256, 0, stream>>>(x, x7b, N);
    k_prepw_all<<<(98304 + 255) / 256, 256, 0, stream>>>(L1[0], L1[2], L2[0], L2[2],
                                                         Wlt1, Wrt1, Wlt2, Wrt2);

    // layer 0: din=7 -> 128 (L2-resident bf16 gather + register-hoisted GEMM)
    k_agg7<<<((size_t)N * 4 + 255) / 256, 256, 0, stream>>>((const unsigned*)x7b,
                                                            off, csr, mean7, N);
    k_layer0<<<(N + 31) / 32, 256, 0, stream>>>(x, mean7, L0[0], L0[1], L0[2], L0[3],
                                                L0[4], L0[5], L0[6], x1, N);

    // layer 1: 128 -> 128, MFMA, in-place on x1 (full-width blocks own their rows)
    k_agg128<<<((size_t)N * 16 + 255) / 256, 256, 0, stream>>>(x1, off, csr, meanb, N);
    k_mfma_layer<128, 128, true><<<dim3(NBX, 1), 256, 0, stream>>>(
        x1, meanb, Wlt1, Wrt1, L1[1], L1[3], L1[4], L1[5], L1[6], x1, N);

    // layer 2: 128 -> 256, MFMA, fp32 out into d_out x-region
    k_agg128<<<((size_t)N * 16 + 255) / 256, 256, 0, stream>>>(x1, off, csr, meanb, N);
    k_mfma_layer<128, 256, false><<<dim3(NBX, 2), 256, 0, stream>>>(
        x1, meanb, Wlt2, Wrt2, L2[1], L2[3], L2[4], L2[5], L2[6], x3, N);

    // global add pool
    k_pool<<<G * 16, 256, 0, stream>>>(x3, gstart, pooled, G);
}

// Round 9
// 426.744 us; speedup vs baseline: 1.1689x; 1.0243x over previous
//
#include <hip/hip_runtime.h>
#include <hip/hip_bf16.h>

#define EPSV 1e-5f
#define PSHIFT 6            // partition = 64 nodes
#define PMASK 63
#define PCAP 1536           // per-partition staging cap (mean 1024, +16 sigma)
#define B1SHIFT 11          // coarse bucket = 2048 nodes = 32 partitions
#define B1MASK ((1 << B1SHIFT) - 1)
#define B1CAP 34816         // per-bucket cap (mean 32768, +11 sigma)
#define SPLIT 16            // scatter2 blocks per coarse bucket

typedef __attribute__((ext_vector_type(8))) short bf16x8;
typedef __attribute__((ext_vector_type(4))) float f32x4;
typedef __attribute__((ext_vector_type(4))) unsigned u32x4;

__device__ __forceinline__ float bf2f(unsigned short u) {
    unsigned x = ((unsigned)u) << 16;
    return __builtin_bit_cast(float, x);
}
__device__ __forceinline__ unsigned short f2bf(float f) {
    unsigned x = __builtin_bit_cast(unsigned, f);
    unsigned r = (x + 0x7fffu + ((x >> 16) & 1u)) >> 16;  // RNE
    return (unsigned short)r;
}
__device__ __forceinline__ float u32lo(unsigned v) {
    return __builtin_bit_cast(float, v << 16);
}
__device__ __forceinline__ float u32hi(unsigned v) {
    return __builtin_bit_cast(float, v & 0xffff0000u);
}
__device__ __forceinline__ f32x4 bflo4(u32x4 v) {
    f32x4 r;
    r.x = __builtin_bit_cast(float, v.x << 16);
    r.y = __builtin_bit_cast(float, v.y << 16);
    r.z = __builtin_bit_cast(float, v.z << 16);
    r.w = __builtin_bit_cast(float, v.w << 16);
    return r;
}
__device__ __forceinline__ f32x4 bfhi4(u32x4 v) {
    f32x4 r;
    r.x = __builtin_bit_cast(float, v.x & 0xffff0000u);
    r.y = __builtin_bit_cast(float, v.y & 0xffff0000u);
    r.z = __builtin_bit_cast(float, v.z & 0xffff0000u);
    r.w = __builtin_bit_cast(float, v.w & 0xffff0000u);
    return r;
}

// ---------------- fused prologue: memsets + x-pack + weight transpose ----------------
// R16: 4 dispatches (2 fills + prepx + prepw) -> 1. All elementwise, disjoint
// outputs, no ordering constraints among them; all must precede scatter1/layer0.

__global__ __launch_bounds__(256) void k_init(
    const float* __restrict__ x, unsigned short* __restrict__ x7b,
    const float* __restrict__ Wl1, const float* __restrict__ Wr1,
    const float* __restrict__ Wl2, const float* __restrict__ Wr2,
    unsigned short* __restrict__ Wlt1, unsigned short* __restrict__ Wrt1,
    unsigned short* __restrict__ Wlt2, unsigned short* __restrict__ Wrt2,
    int* __restrict__ cnts, int ncnt, float* __restrict__ pooled, int n) {
    int u = blockIdx.x * 256 + threadIdx.x;
    if (u < n * 8) {  // x [N,7] fp32 -> x7b [N,8] bf16 (1.6 MB, L2-resident)
        int node = u >> 3, f = u & 7;
        float v = (f < 7) ? x[(size_t)node * 7 + f] : 0.f;
        x7b[u] = f2bf(v);
    }
    if (u < 98304) {  // weight transpose fp32 [K][N] -> bf16 [N][K]
        const float* W;
        unsigned short* Wt;
        int Ncols, v;
        if (u < 32768) {
            v = u & 16383;
            W = (u < 16384) ? Wl1 : Wr1;
            Wt = (u < 16384) ? Wlt1 : Wrt1;
            Ncols = 128;
        } else {
            v = (u - 32768) & 32767;
            W = (u < 65536) ? Wl2 : Wr2;
            Wt = (u < 65536) ? Wlt2 : Wrt2;
            Ncols = 256;
        }
        int nn = v % Ncols, k = v / Ncols;
        Wt[(size_t)nn * 128 + k] = f2bf(W[(size_t)k * Ncols + nn]);
    }
    if (u < ncnt) cnts[u] = 0;
    if (u < 16384) pooled[u] = 0.f;
}

// ---------------- two-level LDS-ranked scatter (R8, verified -42us) ----------------

__global__ __launch_bounds__(256) void k_scatter1(const int* __restrict__ src,
                                                  const int* __restrict__ dst,
                                                  int* __restrict__ bcnt1,
                                                  unsigned* __restrict__ stg1,
                                                  int E, int NB1) {
    __shared__ int hist[64], sbase[64], scur[64];
    int t = threadIdx.x;
    int base = blockIdx.x * 2048;
    if (t < 64) { hist[t] = 0; scur[t] = 0; }
    __syncthreads();
    unsigned val[8];
    int cb[8];
#pragma unroll
    for (int k = 0; k < 8; k++) {
        int i = base + k * 256 + t;
        if (i < E) {
            int d = __builtin_nontemporal_load(&dst[i]);
            int s = __builtin_nontemporal_load(&src[i]);
            cb[k] = d >> B1SHIFT;
            val[k] = ((unsigned)s << B1SHIFT) | (unsigned)(d & B1MASK);
            atomicAdd(&hist[cb[k]], 1);
        } else
            cb[k] = -1;
    }
    __syncthreads();
    if (t < NB1 && hist[t] > 0) sbase[t] = atomicAdd(&bcnt1[t], hist[t]);
    __syncthreads();
#pragma unroll
    for (int k = 0; k < 8; k++) {
        if (cb[k] >= 0) {
            int r = atomicAdd(&scur[cb[k]], 1);
            int slot = sbase[cb[k]] + r;
            if (slot < B1CAP) stg1[(size_t)cb[k] * B1CAP + slot] = val[k];
        }
    }
}

__global__ __launch_bounds__(256) void k_scatter2(const int* __restrict__ bcnt1,
                                                  const unsigned* __restrict__ stg1,
                                                  int* __restrict__ pcnt,
                                                  unsigned* __restrict__ pstg) {
    __shared__ int hist[32], sbase[32], scur[32];
    int cb = blockIdx.x >> 4;  // / SPLIT
    int sl = blockIdx.x & (SPLIT - 1);
    int t = threadIdx.x;
    if (t < 32) { hist[t] = 0; scur[t] = 0; }
    int cnt = min(bcnt1[cb], B1CAP);
    int per = (cnt + SPLIT - 1) / SPLIT;
    int lo = sl * per, hi = min(lo + per, cnt);
    __syncthreads();
    const unsigned* sp = stg1 + (size_t)cb * B1CAP;
    for (int j = lo + t; j < hi; j += 256)
        atomicAdd(&hist[(sp[j] >> 6) & 31], 1);
    __syncthreads();
    if (t < 32 && hist[t] > 0) sbase[t] = atomicAdd(&pcnt[(cb << 5) + t], hist[t]);
    __syncthreads();
    for (int j = lo + t; j < hi; j += 256) {
        unsigned v = sp[j];
        int pr = (v >> 6) & 31;
        int r = atomicAdd(&scur[pr], 1);
        int slot = sbase[pr] + r;
        if (slot < PCAP)
            pstg[(size_t)((cb << 5) + pr) * PCAP + slot] =
                ((v >> 5) & ~63u) | (v & 63u);  // (s<<6)|(d&63)
    }
}

__global__ __launch_bounds__(256) void k_meta(const int* __restrict__ pcnt,
                                              int* __restrict__ pbase,
                                              int* __restrict__ off,
                                              const int* __restrict__ batch,
                                              int* __restrict__ gstart,
                                              int NPART, int Nn, int G) {
    if (blockIdx.x == 1) {
        int g = threadIdx.x;
        if (g > G) return;
        if (g == G) {
            gstart[G] = Nn;
            return;
        }
        int lo = 0, hi = Nn;
        while (lo < hi) {
            int mid = (lo + hi) >> 1;
            if (batch[mid] < g) lo = mid + 1;
            else hi = mid;
        }
        gstart[g] = lo;
        return;
    }
    __shared__ int red[256];
    int t = threadIdx.x;
    int chunk = (NPART + 255) / 256;
    int lo = t * chunk, hi = min(lo + chunk, NPART);
    int s = 0;
    for (int p = lo; p < hi; p++) {
        int tt = min(pcnt[p], PCAP);
        pbase[p] = tt;  // temp: totals
        s += tt;
    }
    red[t] = s;
    __syncthreads();
    for (int d = 1; d < 256; d <<= 1) {
        int v = (t >= d) ? red[t - d] : 0;
        __syncthreads();
        red[t] += v;
        __syncthreads();
    }
    int base = (t == 0) ? 0 : red[t - 1];
    for (int p = lo; p < hi; p++) {
        int tt = pbase[p];
        pbase[p] = base;
        base += tt;
    }
    if (t == 255) off[Nn] = red[255];
}

__global__ __launch_bounds__(256) void k_build(const int* __restrict__ pcnt,
                                               const unsigned* __restrict__ pstg,
                                               const int* __restrict__ pbase,
                                               int* __restrict__ off,
                                               int* __restrict__ csr, int Nn) {
    __shared__ unsigned ed[PCAP];
    __shared__ int srt[PCAP];
    __shared__ int cnt[64], loff[64], cur[64];
    int p = blockIdx.x, t = threadIdx.x;
    int tot = min(pcnt[p], PCAP);
    if (t < 64) cnt[t] = 0;
    __syncthreads();
    const unsigned* sp = pstg + (size_t)p * PCAP;
    for (int j = t; j < tot; j += 256) {
        unsigned e = __builtin_nontemporal_load(&sp[j]);
        ed[j] = e;
        atomicAdd(&cnt[e & PMASK], 1);
    }
    __syncthreads();
    if (t == 0) {
        int a = 0;
        for (int j = 0; j < 64; j++) {
            loff[j] = a;
            cur[j] = a;
            a += cnt[j];
        }
    }
    __syncthreads();
    int base = pbase[p];
    int node0 = p << PSHIFT;
    if (t < 64 && node0 + t < Nn) off[node0 + t] = base + loff[t];
    for (int j = t; j < tot; j += 256) {
        unsigned e = ed[j];
        int pos = atomicAdd(&cur[e & PMASK], 1);
        srt[pos] = (int)(e >> PSHIFT);
    }
    __syncthreads();
    for (int j = t; j < tot; j += 256) csr[base + j] = srt[j];
}

// ---------------- layer 0 fused: agg7 (L2-resident gather) + GEMM ----------------
// R16: fuse is safe here unlike R5 -- x7b is 1.6 MB (L2-resident, short-latency
// gather) and LDS stays at 2 KB so occupancy is unharmed. 32 rows/block:
// phase 1: 128 lanes gather per-node means (4 lanes/node) into ms[][].
// phase 2: weights hoisted to regs, pure FMA + LDS broadcast. Deletes the
// mean7 buffer round-trip and one dispatch.

__global__ __launch_bounds__(256) void k_l0fused(
    const float* __restrict__ x, const unsigned* __restrict__ x7b,
    const int* __restrict__ off, const int* __restrict__ csr,
    const float* __restrict__ Wl, const float* __restrict__ bl,
    const float* __restrict__ Wr, const float* __restrict__ g,
    const float* __restrict__ be, const float* __restrict__ rm,
    const float* __restrict__ rv, unsigned short* __restrict__ out, int n) {
    __shared__ float xs[32][8];
    __shared__ float ms[32][8];
    int tid = threadIdx.x;
    int row0 = blockIdx.x * 32;

    if (tid < 224) {  // stage self rows: 32 x 7 fp32, coalesced
        int r = tid / 7, f = tid % 7;
        int gr = row0 + r;
        xs[r][f] = (gr < n) ? x[(size_t)gr * 7 + f] : 0.f;
    }
    if (tid < 128) {  // gather means: 4 lanes/node, x7b L2-resident
        int r = tid >> 2, lane = tid & 3;
        int grow = row0 + r;
        float a0 = 0.f, a1 = 0.f, inv = 0.f;
        if (grow < n) {
            int a = off[grow], b = off[grow + 1];
            int j = a;
            for (; j + 3 < b; j += 4) {
                unsigned v0 = x7b[(size_t)csr[j] * 4 + lane];
                unsigned v1 = x7b[(size_t)csr[j + 1] * 4 + lane];
                unsigned v2 = x7b[(size_t)csr[j + 2] * 4 + lane];
                unsigned v3 = x7b[(size_t)csr[j + 3] * 4 + lane];
                a0 += u32lo(v0) + u32lo(v1) + u32lo(v2) + u32lo(v3);
                a1 += u32hi(v0) + u32hi(v1) + u32hi(v2) + u32hi(v3);
            }
            for (; j < b; j++) {
                unsigned v = x7b[(size_t)csr[j] * 4 + lane];
                a0 += u32lo(v);
                a1 += u32hi(v);
            }
            inv = 1.0f / (float)max(b - a, 1);
        }
        ms[r][lane * 2] = a0 * inv;
        ms[r][lane * 2 + 1] = a1 * inv;
    }

    int col = tid & 127;
    float wl[7], wr[7];
#pragma unroll
    for (int k = 0; k < 7; k++) {
        wl[k] = Wl[k * 128 + col];
        wr[k] = Wr[k * 128 + col];
    }
    float sc = g[col] * rsqrtf(rv[col] + EPSV);
    float sh = (bl[col] - rm[col]) * sc + be[col];
    __syncthreads();

    int hr = tid >> 7;  // 0: rows 0-15, 1: rows 16-31
#pragma unroll
    for (int rr = 0; rr < 16; rr++) {
        int r = hr * 16 + rr;
        int grow = row0 + r;
        if (grow >= n) break;
        float acc = 0.f;
#pragma unroll
        for (int k = 0; k < 7; k++) acc = fmaf(xs[r][k], wl[k], acc);
#pragma unroll
        for (int k = 0; k < 7; k++) acc = fmaf(ms[r][k], wr[k], acc);
        float h = acc * sc + sh;
        out[(size_t)grow * 128 + col] = f2bf(fmaxf(h, 0.f));
    }
}

// R13 = R9's best-measured gather (60.6us): 16 lanes/node, 16B loads, 4-deep.
__global__ __launch_bounds__(256) void k_agg128(const unsigned short* __restrict__ x,
                                                const int* __restrict__ off,
                                                const int* __restrict__ csr,
                                                unsigned short* __restrict__ mean,
                                                int n) {
    int q = (blockIdx.x * 256 + threadIdx.x) >> 4;  // quarter-wave = node
    int sl = threadIdx.x & 15;
    if (q >= n) return;
    int a = off[q], b = off[q + 1];
    const u32x4* xr = (const u32x4*)x;  // 16 x 16B per 128-col row
    f32x4 aL = {0.f, 0.f, 0.f, 0.f}, aH = {0.f, 0.f, 0.f, 0.f};
    int j = a;
    for (; j + 3 < b; j += 4) {
        int s0 = csr[j], s1 = csr[j + 1], s2 = csr[j + 2], s3 = csr[j + 3];
        u32x4 v0 = xr[(size_t)s0 * 16 + sl];
        u32x4 v1 = xr[(size_t)s1 * 16 + sl];
        u32x4 v2 = xr[(size_t)s2 * 16 + sl];
        u32x4 v3 = xr[(size_t)s3 * 16 + sl];
        aL += bflo4(v0) + bflo4(v1) + bflo4(v2) + bflo4(v3);
        aH += bfhi4(v0) + bfhi4(v1) + bfhi4(v2) + bfhi4(v3);
    }
    for (; j < b; j++) {
        u32x4 v = xr[(size_t)csr[j] * 16 + sl];
        aL += bflo4(v);
        aH += bfhi4(v);
    }
    float inv = 1.0f / (float)max(b - a, 1);
    u32x4 o;
    o.x = (unsigned)f2bf(aL.x * inv) | ((unsigned)f2bf(aH.x * inv) << 16);
    o.y = (unsigned)f2bf(aL.y * inv) | ((unsigned)f2bf(aH.y * inv) << 16);
    o.z = (unsigned)f2bf(aL.z * inv) | ((unsigned)f2bf(aH.z * inv) << 16);
    o.w = (unsigned)f2bf(aL.w * inv) | ((unsigned)f2bf(aH.w * inv) << 16);
    *((u32x4*)mean + (size_t)q * 16 + sl) = o;
}

// ---------------- MFMA layer (pure R11 core -- measured best) ----------------
// Pool fusion attempted 3x (R2/R3/R6), regressed every time; pooling stays in
// k_pool. 64 rows x COLS(=128) per block, simple 8-stage loop.

template <int COLS, int DOUT, bool BF16OUT>
__global__ __launch_bounds__(256) void k_mfma_layer(
    const unsigned short* __restrict__ xin, const unsigned short* __restrict__ meanb,
    const unsigned short* __restrict__ Wlt, const unsigned short* __restrict__ Wrt,
    const float* __restrict__ bl, const float* __restrict__ g,
    const float* __restrict__ be, const float* __restrict__ rm,
    const float* __restrict__ rv, void* __restrict__ outv, int n) {
    __shared__ unsigned short As[64 * 40];
    __shared__ unsigned short Bs[COLS * 40];

    int tid = threadIdx.x;
    int wave = tid >> 6;
    int lane = tid & 63;
    int m = lane & 15;
    int half = lane >> 4;
    int row0 = blockIdx.x * 64;
    int colbase = blockIdx.y * COLS;

    const int NCB = COLS / 16;
    f32x4 acc[NCB] = {};

    for (int s = 0; s < 8; s++) {
        int pass = s >> 2;
        int k0 = (s & 3) * 32;
        const unsigned short* Asrc = pass ? meanb : xin;
        const unsigned short* Wt = pass ? Wrt : Wlt;

        __syncthreads();
        {   // stage A: 64 rows x 32 k
            int rr = tid >> 2;
            int ks = (tid & 3) * 8;
            int grow = row0 + rr;
            float4 v = make_float4(0.f, 0.f, 0.f, 0.f);
            if (grow < n) v = *(const float4*)&Asrc[(size_t)grow * 128 + k0 + ks];
            *(float4*)&As[rr * 40 + ks] = v;
        }
#pragma unroll
        for (int rep = 0; rep < COLS / 64; rep++) {  // stage B: COLS cols x 32 k
            int u = tid + rep * 256;
            int nn = u >> 2;
            int ks = (u & 3) * 8;
            float4 v = *(const float4*)&Wt[(size_t)(colbase + nn) * 128 + k0 + ks];
            *(float4*)&Bs[nn * 40 + ks] = v;
        }
        __syncthreads();

        bf16x8 a = *(const bf16x8*)&As[(wave * 16 + m) * 40 + half * 8];
#pragma unroll
        for (int cb = 0; cb < NCB; cb++) {
            bf16x8 b = *(const bf16x8*)&Bs[(cb * 16 + m) * 40 + half * 8];
            acc[cb] = __builtin_amdgcn_mfma_f32_16x16x32_bf16(a, b, acc[cb], 0, 0, 0);
        }
    }

    float* outf = (float*)outv;
    unsigned short* outb = (unsigned short*)outv;
#pragma unroll
    for (int cb = 0; cb < NCB; cb++) {
        int col = colbase + cb * 16 + m;
        float sc = g[col] * rsqrtf(rv[col] + EPSV);
        float sh = (bl[col] - rm[col]) * sc + be[col];
#pragma unroll
        for (int reg = 0; reg < 4; reg++) {
            int r0 = row0 + wave * 16 + half * 4 + reg;
            if (r0 < n) {
                float h = fmaxf(acc[cb][reg] * sc + sh, 0.f);
                if (BF16OUT) outb[(size_t)r0 * DOUT + col] = f2bf(h);
                else outf[(size_t)r0 * DOUT + col] = h;
            }
        }
    }
}

// ---------------- pooling ----------------

__global__ __launch_bounds__(256) void k_pool(const float* __restrict__ x3,
                                              const int* __restrict__ gstart,
                                              float* __restrict__ pooled, int G) {
    const int S = 16;
    int g = blockIdx.x / S;
    int s = blockIdx.x % S;
    int a = gstart[g], b = gstart[g + 1];
    int col = threadIdx.x;
    float acc = 0.f;
    for (int r = a + s; r < b; r += S) acc += x3[(size_t)r * 256 + col];
    atomicAdd(&pooled[g * 256 + col], acc);
}

// ---------------- launch ----------------

extern "C" void kernel_launch(void* const* d_in, const int* in_sizes, int n_in,
                              void* d_out, int out_size, void* d_ws, size_t ws_size,
                              hipStream_t stream) {
    const float* x = (const float*)d_in[0];
    const int* ei = (const int*)d_in[1];
    const int* batch = (const int*)d_in[2];
    const int N = in_sizes[0] / 7;
    const int E = in_sizes[1] / 2;
    const int G = 64;
    const int* src = ei;
    const int* dst = ei + E;
    const int NPART = (N + PMASK) >> PSHIFT;
    const int NB1 = (N + (1 << B1SHIFT) - 1) >> B1SHIFT;
    const int NBX = (N + 63) / 64;

    const float* P[21];
    for (int i = 0; i < 21; i++) P[i] = (const float*)d_in[3 + i];
    const float **L0 = P, **L1 = P + 7, **L2 = P + 14;

    char* w = (char*)d_ws;
    auto carve = [&](size_t bytes) {
        void* p = (void*)w;
        w += (bytes + 255) & ~(size_t)255;
        return p;
    };
    int* cnts = (int*)carve((size_t)(64 + NPART) * 4);  // bcnt1[64] + pcnt[NPART]
    int* bcnt1 = cnts;
    int* pcnt = cnts + 64;
    unsigned* stg1 = (unsigned*)carve((size_t)NB1 * B1CAP * 4);
    unsigned* pstg = (unsigned*)carve((size_t)NPART * PCAP * 4);
    int* pbase = (int*)carve((size_t)NPART * 4);
    int* off = (int*)carve(((size_t)N + 1) * 4);
    int* gstart = (int*)carve(((size_t)G + 1) * 4);
    unsigned short* x7b = (unsigned short*)carve((size_t)N * 8 * 2);
    unsigned short* x1 = (unsigned short*)carve((size_t)N * 128 * 2);
    unsigned short* meanb = (unsigned short*)carve((size_t)N * 128 * 2);
    unsigned short* Wlt1 = (unsigned short*)carve((size_t)128 * 128 * 2);
    unsigned short* Wrt1 = (unsigned short*)carve((size_t)128 * 128 * 2);
    unsigned short* Wlt2 = (unsigned short*)carve((size_t)128 * 256 * 2);
    unsigned short* Wrt2 = (unsigned short*)carve((size_t)128 * 256 * 2);
    // csr aliases stg1: stg1 is dead after k_scatter2 completes, and k_build
    // (same stream) is the first writer of csr.
    int* csr = (int*)stg1;

    float* pooled = (float*)d_out;
    float* x3 = (float*)d_out + (size_t)G * 256;

    // fused prologue (replaces 2 memsets + prepx + prepw dispatches)
    int initN = max(N * 8, 98304);
    k_init<<<(initN + 255) / 256, 256, 0, stream>>>(
        x, x7b, L1[0], L1[2], L2[0], L2[2], Wlt1, Wrt1, Wlt2, Wrt2,
        cnts, 64 + NPART, pooled, N);

    // CSR build: two-level LDS-ranked scatter + meta + partition sort
    k_scatter1<<<(E + 2047) / 2048, 256, 0, stream>>>(src, dst, bcnt1, stg1, E, NB1);
    k_scatter2<<<NB1 * SPLIT, 256, 0, stream>>>(bcnt1, stg1, pcnt, pstg);
    k_meta<<<2, 256, 0, stream>>>(pcnt, pbase, off, batch, gstart, NPART, N, G);
    k_build<<<NPART, 256, 0, stream>>>(pcnt, pstg, pbase, off, csr, N);

    // layer 0: fused L2-resident gather + register-hoisted GEMM
    k_l0fused<<<(N + 31) / 32, 256, 0, stream>>>(
        x, (const unsigned*)x7b, off, csr, L0[0], L0[1], L0[2], L0[3],
        L0[4], L0[5], L0[6], x1, N);

    // layer 1: 128 -> 128, MFMA, in-place on x1 (full-width blocks own their rows)
    k_agg128<<<((size_t)N * 16 + 255) / 256, 256, 0, stream>>>(x1, off, csr, meanb, N);
    k_mfma_layer<128, 128, true><<<dim3(NBX, 1), 256, 0, stream>>>(
        x1, meanb, Wlt1, Wrt1, L1[1], L1[3], L1[4], L1[5], L1[6], x1, N);

    // layer 2: 128 -> 256, MFMA, fp32 out into d_out x-region
    k_agg128<<<((size_t)N * 16 + 255) / 256, 256, 0, stream>>>(x1, off, csr, meanb, N);
    k_mfma_layer<128, 256, false><<<dim3(NBX, 2), 256, 0, stream>>>(
        x1, meanb, Wlt2, Wrt2, L2[1], L2[3], L2[4], L2[5], L2[6], x3, N);

    // global add pool
    k_pool<<<G * 16, 256, 0, stream>>>(x3, gstart, pooled, G);
}

// Round 10
// 424.815 us; speedup vs baseline: 1.1742x; 1.0045x over previous
//
#include <hip/hip_runtime.h>
#include <hip/hip_bf16.h>

#define EPSV 1e-5f
#define PSHIFT 6            // partition = 64 nodes
#define PMASK 63
#define PCAP 1536           // per-partition staging cap (mean 1024, +16 sigma)
#define B1SHIFT 11          // coarse bucket = 2048 nodes = 32 partitions
#define B1MASK ((1 << B1SHIFT) - 1)
#define B1CAP 34816         // per-bucket cap (mean 32768, +11 sigma)
#define SPLIT 16            // scatter2 blocks per coarse bucket

typedef __attribute__((ext_vector_type(8))) short bf16x8;
typedef __attribute__((ext_vector_type(4))) float f32x4;
typedef __attribute__((ext_vector_type(4))) unsigned u32x4;

__device__ __forceinline__ float bf2f(unsigned short u) {
    unsigned x = ((unsigned)u) << 16;
    return __builtin_bit_cast(float, x);
}
__device__ __forceinline__ unsigned short f2bf(float f) {
    unsigned x = __builtin_bit_cast(unsigned, f);
    unsigned r = (x + 0x7fffu + ((x >> 16) & 1u)) >> 16;  // RNE
    return (unsigned short)r;
}
__device__ __forceinline__ float u32lo(unsigned v) {
    return __builtin_bit_cast(float, v << 16);
}
__device__ __forceinline__ float u32hi(unsigned v) {
    return __builtin_bit_cast(float, v & 0xffff0000u);
}
__device__ __forceinline__ f32x4 bflo4(u32x4 v) {
    f32x4 r;
    r.x = __builtin_bit_cast(float, v.x << 16);
    r.y = __builtin_bit_cast(float, v.y << 16);
    r.z = __builtin_bit_cast(float, v.z << 16);
    r.w = __builtin_bit_cast(float, v.w << 16);
    return r;
}
__device__ __forceinline__ f32x4 bfhi4(u32x4 v) {
    f32x4 r;
    r.x = __builtin_bit_cast(float, v.x & 0xffff0000u);
    r.y = __builtin_bit_cast(float, v.y & 0xffff0000u);
    r.z = __builtin_bit_cast(float, v.z & 0xffff0000u);
    r.w = __builtin_bit_cast(float, v.w & 0xffff0000u);
    return r;
}

// ---------------- fused prologue: memsets + x-pack + weight transpose ----------------
// R16 (verified): 4 dispatches -> 1.

__global__ __launch_bounds__(256) void k_init(
    const float* __restrict__ x, unsigned short* __restrict__ x7b,
    const float* __restrict__ Wl1, const float* __restrict__ Wr1,
    const float* __restrict__ Wl2, const float* __restrict__ Wr2,
    unsigned short* __restrict__ Wlt1, unsigned short* __restrict__ Wrt1,
    unsigned short* __restrict__ Wlt2, unsigned short* __restrict__ Wrt2,
    int* __restrict__ cnts, int ncnt, float* __restrict__ pooled, int n) {
    int u = blockIdx.x * 256 + threadIdx.x;
    if (u < n * 8) {  // x [N,7] fp32 -> x7b [N,8] bf16 (1.6 MB, L2-resident)
        int node = u >> 3, f = u & 7;
        float v = (f < 7) ? x[(size_t)node * 7 + f] : 0.f;
        x7b[u] = f2bf(v);
    }
    if (u < 98304) {  // weight transpose fp32 [K][N] -> bf16 [N][K]
        const float* W;
        unsigned short* Wt;
        int Ncols, v;
        if (u < 32768) {
            v = u & 16383;
            W = (u < 16384) ? Wl1 : Wr1;
            Wt = (u < 16384) ? Wlt1 : Wrt1;
            Ncols = 128;
        } else {
            v = (u - 32768) & 32767;
            W = (u < 65536) ? Wl2 : Wr2;
            Wt = (u < 65536) ? Wlt2 : Wrt2;
            Ncols = 256;
        }
        int nn = v % Ncols, k = v / Ncols;
        Wt[(size_t)nn * 128 + k] = f2bf(W[(size_t)k * Ncols + nn]);
    }
    if (u < ncnt) cnts[u] = 0;
    if (u < 16384) pooled[u] = 0.f;
}

// ---------------- two-level LDS-ranked scatter (R8, verified -42us) ----------------

__global__ __launch_bounds__(256) void k_scatter1(const int* __restrict__ src,
                                                  const int* __restrict__ dst,
                                                  int* __restrict__ bcnt1,
                                                  unsigned* __restrict__ stg1,
                                                  int E, int NB1) {
    __shared__ int hist[64], sbase[64], scur[64];
    int t = threadIdx.x;
    int base = blockIdx.x * 2048;
    if (t < 64) { hist[t] = 0; scur[t] = 0; }
    __syncthreads();
    unsigned val[8];
    int cb[8];
#pragma unroll
    for (int k = 0; k < 8; k++) {
        int i = base + k * 256 + t;
        if (i < E) {
            int d = __builtin_nontemporal_load(&dst[i]);
            int s = __builtin_nontemporal_load(&src[i]);
            cb[k] = d >> B1SHIFT;
            val[k] = ((unsigned)s << B1SHIFT) | (unsigned)(d & B1MASK);
            atomicAdd(&hist[cb[k]], 1);
        } else
            cb[k] = -1;
    }
    __syncthreads();
    if (t < NB1 && hist[t] > 0) sbase[t] = atomicAdd(&bcnt1[t], hist[t]);
    __syncthreads();
#pragma unroll
    for (int k = 0; k < 8; k++) {
        if (cb[k] >= 0) {
            int r = atomicAdd(&scur[cb[k]], 1);
            int slot = sbase[cb[k]] + r;
            if (slot < B1CAP) stg1[(size_t)cb[k] * B1CAP + slot] = val[k];
        }
    }
}

__global__ __launch_bounds__(256) void k_scatter2(const int* __restrict__ bcnt1,
                                                  const unsigned* __restrict__ stg1,
                                                  int* __restrict__ pcnt,
                                                  unsigned* __restrict__ pstg) {
    __shared__ int hist[32], sbase[32], scur[32];
    int cb = blockIdx.x >> 4;  // / SPLIT
    int sl = blockIdx.x & (SPLIT - 1);
    int t = threadIdx.x;
    if (t < 32) { hist[t] = 0; scur[t] = 0; }
    int cnt = min(bcnt1[cb], B1CAP);
    int per = (cnt + SPLIT - 1) / SPLIT;
    int lo = sl * per, hi = min(lo + per, cnt);
    __syncthreads();
    const unsigned* sp = stg1 + (size_t)cb * B1CAP;
    for (int j = lo + t; j < hi; j += 256)
        atomicAdd(&hist[(sp[j] >> 6) & 31], 1);
    __syncthreads();
    if (t < 32 && hist[t] > 0) sbase[t] = atomicAdd(&pcnt[(cb << 5) + t], hist[t]);
    __syncthreads();
    for (int j = lo + t; j < hi; j += 256) {
        unsigned v = sp[j];
        int pr = (v >> 6) & 31;
        int r = atomicAdd(&scur[pr], 1);
        int slot = sbase[pr] + r;
        if (slot < PCAP)
            pstg[(size_t)((cb << 5) + pr) * PCAP + slot] =
                ((v >> 5) & ~63u) | (v & 63u);  // (s<<6)|(d&63)
    }
}

__global__ __launch_bounds__(256) void k_meta(const int* __restrict__ pcnt,
                                              int* __restrict__ pbase,
                                              int* __restrict__ off,
                                              const int* __restrict__ batch,
                                              int* __restrict__ gstart,
                                              int NPART, int Nn, int G) {
    if (blockIdx.x == 1) {
        int g = threadIdx.x;
        if (g > G) return;
        if (g == G) {
            gstart[G] = Nn;
            return;
        }
        int lo = 0, hi = Nn;
        while (lo < hi) {
            int mid = (lo + hi) >> 1;
            if (batch[mid] < g) lo = mid + 1;
            else hi = mid;
        }
        gstart[g] = lo;
        return;
    }
    __shared__ int red[256];
    int t = threadIdx.x;
    int chunk = (NPART + 255) / 256;
    int lo = t * chunk, hi = min(lo + chunk, NPART);
    int s = 0;
    for (int p = lo; p < hi; p++) {
        int tt = min(pcnt[p], PCAP);
        pbase[p] = tt;  // temp: totals
        s += tt;
    }
    red[t] = s;
    __syncthreads();
    for (int d = 1; d < 256; d <<= 1) {
        int v = (t >= d) ? red[t - d] : 0;
        __syncthreads();
        red[t] += v;
        __syncthreads();
    }
    int base = (t == 0) ? 0 : red[t - 1];
    for (int p = lo; p < hi; p++) {
        int tt = pbase[p];
        pbase[p] = base;
        base += tt;
    }
    if (t == 255) off[Nn] = red[255];
}

__global__ __launch_bounds__(256) void k_build(const int* __restrict__ pcnt,
                                               const unsigned* __restrict__ pstg,
                                               const int* __restrict__ pbase,
                                               int* __restrict__ off,
                                               int* __restrict__ csr, int Nn) {
    __shared__ unsigned ed[PCAP];
    __shared__ int srt[PCAP];
    __shared__ int cnt[64], loff[64], cur[64];
    int p = blockIdx.x, t = threadIdx.x;
    int tot = min(pcnt[p], PCAP);
    if (t < 64) cnt[t] = 0;
    __syncthreads();
    const unsigned* sp = pstg + (size_t)p * PCAP;
    for (int j = t; j < tot; j += 256) {
        unsigned e = __builtin_nontemporal_load(&sp[j]);
        ed[j] = e;
        atomicAdd(&cnt[e & PMASK], 1);
    }
    __syncthreads();
    if (t == 0) {
        int a = 0;
        for (int j = 0; j < 64; j++) {
            loff[j] = a;
            cur[j] = a;
            a += cnt[j];
        }
    }
    __syncthreads();
    int base = pbase[p];
    int node0 = p << PSHIFT;
    if (t < 64 && node0 + t < Nn) off[node0 + t] = base + loff[t];
    for (int j = t; j < tot; j += 256) {
        unsigned e = ed[j];
        int pos = atomicAdd(&cur[e & PMASK], 1);
        srt[pos] = (int)(e >> PSHIFT);
    }
    __syncthreads();
    for (int j = t; j < tot; j += 256) csr[base + j] = srt[j];
}

// ---------------- layer 0 fused: agg7 (L2-resident gather) + GEMM (R16, verified) ----

__global__ __launch_bounds__(256) void k_l0fused(
    const float* __restrict__ x, const unsigned* __restrict__ x7b,
    const int* __restrict__ off, const int* __restrict__ csr,
    const float* __restrict__ Wl, const float* __restrict__ bl,
    const float* __restrict__ Wr, const float* __restrict__ g,
    const float* __restrict__ be, const float* __restrict__ rm,
    const float* __restrict__ rv, unsigned short* __restrict__ out, int n) {
    __shared__ float xs[32][8];
    __shared__ float ms[32][8];
    int tid = threadIdx.x;
    int row0 = blockIdx.x * 32;

    if (tid < 224) {  // stage self rows: 32 x 7 fp32, coalesced
        int r = tid / 7, f = tid % 7;
        int gr = row0 + r;
        xs[r][f] = (gr < n) ? x[(size_t)gr * 7 + f] : 0.f;
    }
    if (tid < 128) {  // gather means: 4 lanes/node, x7b L2-resident
        int r = tid >> 2, lane = tid & 3;
        int grow = row0 + r;
        float a0 = 0.f, a1 = 0.f, inv = 0.f;
        if (grow < n) {
            int a = off[grow], b = off[grow + 1];
            int j = a;
            for (; j + 3 < b; j += 4) {
                unsigned v0 = x7b[(size_t)csr[j] * 4 + lane];
                unsigned v1 = x7b[(size_t)csr[j + 1] * 4 + lane];
                unsigned v2 = x7b[(size_t)csr[j + 2] * 4 + lane];
                unsigned v3 = x7b[(size_t)csr[j + 3] * 4 + lane];
                a0 += u32lo(v0) + u32lo(v1) + u32lo(v2) + u32lo(v3);
                a1 += u32hi(v0) + u32hi(v1) + u32hi(v2) + u32hi(v3);
            }
            for (; j < b; j++) {
                unsigned v = x7b[(size_t)csr[j] * 4 + lane];
                a0 += u32lo(v);
                a1 += u32hi(v);
            }
            inv = 1.0f / (float)max(b - a, 1);
        }
        ms[r][lane * 2] = a0 * inv;
        ms[r][lane * 2 + 1] = a1 * inv;
    }

    int col = tid & 127;
    float wl[7], wr[7];
#pragma unroll
    for (int k = 0; k < 7; k++) {
        wl[k] = Wl[k * 128 + col];
        wr[k] = Wr[k * 128 + col];
    }
    float sc = g[col] * rsqrtf(rv[col] + EPSV);
    float sh = (bl[col] - rm[col]) * sc + be[col];
    __syncthreads();

    int hr = tid >> 7;  // 0: rows 0-15, 1: rows 16-31
#pragma unroll
    for (int rr = 0; rr < 16; rr++) {
        int r = hr * 16 + rr;
        int grow = row0 + r;
        if (grow >= n) break;
        float acc = 0.f;
#pragma unroll
        for (int k = 0; k < 7; k++) acc = fmaf(xs[r][k], wl[k], acc);
#pragma unroll
        for (int k = 0; k < 7; k++) acc = fmaf(ms[r][k], wr[k], acc);
        float h = acc * sc + sh;
        out[(size_t)grow * 128 + col] = f2bf(fmaxf(h, 0.f));
    }
}

// R13 = R9's best-measured gather (60.6us): 16 lanes/node, 16B loads, 4-deep.
__global__ __launch_bounds__(256) void k_agg128(const unsigned short* __restrict__ x,
                                                const int* __restrict__ off,
                                                const int* __restrict__ csr,
                                                unsigned short* __restrict__ mean,
                                                int n) {
    int q = (blockIdx.x * 256 + threadIdx.x) >> 4;  // quarter-wave = node
    int sl = threadIdx.x & 15;
    if (q >= n) return;
    int a = off[q], b = off[q + 1];
    const u32x4* xr = (const u32x4*)x;  // 16 x 16B per 128-col row
    f32x4 aL = {0.f, 0.f, 0.f, 0.f}, aH = {0.f, 0.f, 0.f, 0.f};
    int j = a;
    for (; j + 3 < b; j += 4) {
        int s0 = csr[j], s1 = csr[j + 1], s2 = csr[j + 2], s3 = csr[j + 3];
        u32x4 v0 = xr[(size_t)s0 * 16 + sl];
        u32x4 v1 = xr[(size_t)s1 * 16 + sl];
        u32x4 v2 = xr[(size_t)s2 * 16 + sl];
        u32x4 v3 = xr[(size_t)s3 * 16 + sl];
        aL += bflo4(v0) + bflo4(v1) + bflo4(v2) + bflo4(v3);
        aH += bfhi4(v0) + bfhi4(v1) + bfhi4(v2) + bfhi4(v3);
    }
    for (; j < b; j++) {
        u32x4 v = xr[(size_t)csr[j] * 16 + sl];
        aL += bflo4(v);
        aH += bfhi4(v);
    }
    float inv = 1.0f / (float)max(b - a, 1);
    u32x4 o;
    o.x = (unsigned)f2bf(aL.x * inv) | ((unsigned)f2bf(aH.x * inv) << 16);
    o.y = (unsigned)f2bf(aL.y * inv) | ((unsigned)f2bf(aH.y * inv) << 16);
    o.z = (unsigned)f2bf(aL.z * inv) | ((unsigned)f2bf(aH.z * inv) << 16);
    o.w = (unsigned)f2bf(aL.w * inv) | ((unsigned)f2bf(aH.w * inv) << 16);
    *((u32x4*)mean + (size_t)q * 16 + sl) = o;
}

// ---------------- MFMA layer: R17 -- both passes per k0 stage ----------------
// R6 counters: MfmaUtil 5%, VALUBusy 12%, occupancy 33%, HBM 22% -- not BW
// bound (floor 12/24us vs 50/58 measured); barrier-exposed global latency with
// only 8 MFMA/wave between barriers. R17: 4 stages (k0=0..96), each stages
// BOTH A tiles (xin, meanb) + BOTH B tiles (Wl, Wr) -> 16 MFMA/wave per
// barrier pair, half the barriers, same traffic. LDS 30.7KB (5 blocks/CU).
// Pool fusion stays OUT (R2/R3/R6 all regressed).

template <int COLS, int DOUT, bool BF16OUT>
__global__ __launch_bounds__(256) void k_mfma_layer(
    const unsigned short* __restrict__ xin, const unsigned short* __restrict__ meanb,
    const unsigned short* __restrict__ Wlt, const unsigned short* __restrict__ Wrt,
    const float* __restrict__ bl, const float* __restrict__ g,
    const float* __restrict__ be, const float* __restrict__ rm,
    const float* __restrict__ rv, void* __restrict__ outv, int n) {
    __shared__ unsigned short As[2][64 * 40];
    __shared__ unsigned short Bs[2][COLS * 40];

    int tid = threadIdx.x;
    int wave = tid >> 6;
    int lane = tid & 63;
    int m = lane & 15;
    int half = lane >> 4;
    int row0 = blockIdx.x * 64;
    int colbase = blockIdx.y * COLS;

    const int NCB = COLS / 16;
    f32x4 acc[NCB] = {};

    int rr = tid >> 2;
    int ks = (tid & 3) * 8;

    for (int s = 0; s < 4; s++) {
        int k0 = s * 32;

        __syncthreads();
        {   // stage A: 64 rows x 32 k, both passes (independent loads -> MLP)
            int grow = row0 + rr;
            float4 vx = make_float4(0.f, 0.f, 0.f, 0.f);
            float4 vm = vx;
            if (grow < n) {
                vx = *(const float4*)&xin[(size_t)grow * 128 + k0 + ks];
                vm = *(const float4*)&meanb[(size_t)grow * 128 + k0 + ks];
            }
            *(float4*)&As[0][rr * 40 + ks] = vx;
            *(float4*)&As[1][rr * 40 + ks] = vm;
        }
#pragma unroll
        for (int rep = 0; rep < COLS / 64; rep++) {  // stage B: both weights
            int u = tid + rep * 256;
            int nn = u >> 2;
            int ks2 = (u & 3) * 8;
            float4 vl = *(const float4*)&Wlt[(size_t)(colbase + nn) * 128 + k0 + ks2];
            float4 vr = *(const float4*)&Wrt[(size_t)(colbase + nn) * 128 + k0 + ks2];
            *(float4*)&Bs[0][nn * 40 + ks2] = vl;
            *(float4*)&Bs[1][nn * 40 + ks2] = vr;
        }
        __syncthreads();

#pragma unroll
        for (int p = 0; p < 2; p++) {
            bf16x8 a = *(const bf16x8*)&As[p][(wave * 16 + m) * 40 + half * 8];
#pragma unroll
            for (int cb = 0; cb < NCB; cb++) {
                bf16x8 b = *(const bf16x8*)&Bs[p][(cb * 16 + m) * 40 + half * 8];
                acc[cb] = __builtin_amdgcn_mfma_f32_16x16x32_bf16(a, b, acc[cb], 0, 0, 0);
            }
        }
    }

    float* outf = (float*)outv;
    unsigned short* outb = (unsigned short*)outv;
#pragma unroll
    for (int cb = 0; cb < NCB; cb++) {
        int col = colbase + cb * 16 + m;
        float sc = g[col] * rsqrtf(rv[col] + EPSV);
        float sh = (bl[col] - rm[col]) * sc + be[col];
#pragma unroll
        for (int reg = 0; reg < 4; reg++) {
            int r0 = row0 + wave * 16 + half * 4 + reg;
            if (r0 < n) {
                float h = fmaxf(acc[cb][reg] * sc + sh, 0.f);
                if (BF16OUT) outb[(size_t)r0 * DOUT + col] = f2bf(h);
                else outf[(size_t)r0 * DOUT + col] = h;
            }
        }
    }
}

// ---------------- pooling ----------------

__global__ __launch_bounds__(256) void k_pool(const float* __restrict__ x3,
                                              const int* __restrict__ gstart,
                                              float* __restrict__ pooled, int G) {
    const int S = 16;
    int g = blockIdx.x / S;
    int s = blockIdx.x % S;
    int a = gstart[g], b = gstart[g + 1];
    int col = threadIdx.x;
    float acc = 0.f;
    for (int r = a + s; r < b; r += S) acc += x3[(size_t)r * 256 + col];
    atomicAdd(&pooled[g * 256 + col], acc);
}

// ---------------- launch ----------------

extern "C" void kernel_launch(void* const* d_in, const int* in_sizes, int n_in,
                              void* d_out, int out_size, void* d_ws, size_t ws_size,
                              hipStream_t stream) {
    const float* x = (const float*)d_in[0];
    const int* ei = (const int*)d_in[1];
    const int* batch = (const int*)d_in[2];
    const int N = in_sizes[0] / 7;
    const int E = in_sizes[1] / 2;
    const int G = 64;
    const int* src = ei;
    const int* dst = ei + E;
    const int NPART = (N + PMASK) >> PSHIFT;
    const int NB1 = (N + (1 << B1SHIFT) - 1) >> B1SHIFT;
    const int NBX = (N + 63) / 64;

    const float* P[21];
    for (int i = 0; i < 21; i++) P[i] = (const float*)d_in[3 + i];
    const float **L0 = P, **L1 = P + 7, **L2 = P + 14;

    char* w = (char*)d_ws;
    auto carve = [&](size_t bytes) {
        void* p = (void*)w;
        w += (bytes + 255) & ~(size_t)255;
        return p;
    };
    int* cnts = (int*)carve((size_t)(64 + NPART) * 4);  // bcnt1[64] + pcnt[NPART]
    int* bcnt1 = cnts;
    int* pcnt = cnts + 64;
    unsigned* stg1 = (unsigned*)carve((size_t)NB1 * B1CAP * 4);
    unsigned* pstg = (unsigned*)carve((size_t)NPART * PCAP * 4);
    int* pbase = (int*)carve((size_t)NPART * 4);
    int* off = (int*)carve(((size_t)N + 1) * 4);
    int* gstart = (int*)carve(((size_t)G + 1) * 4);
    unsigned short* x7b = (unsigned short*)carve((size_t)N * 8 * 2);
    unsigned short* x1 = (unsigned short*)carve((size_t)N * 128 * 2);
    unsigned short* meanb = (unsigned short*)carve((size_t)N * 128 * 2);
    unsigned short* Wlt1 = (unsigned short*)carve((size_t)128 * 128 * 2);
    unsigned short* Wrt1 = (unsigned short*)carve((size_t)128 * 128 * 2);
    unsigned short* Wlt2 = (unsigned short*)carve((size_t)128 * 256 * 2);
    unsigned short* Wrt2 = (unsigned short*)carve((size_t)128 * 256 * 2);
    // csr aliases stg1: stg1 is dead after k_scatter2 completes, and k_build
    // (same stream) is the first writer of csr.
    int* csr = (int*)stg1;

    float* pooled = (float*)d_out;
    float* x3 = (float*)d_out + (size_t)G * 256;

    // fused prologue (replaces 2 memsets + prepx + prepw dispatches)
    int initN = max(N * 8, 98304);
    k_init<<<(initN + 255) / 256, 256, 0, stream>>>(
        x, x7b, L1[0], L1[2], L2[0], L2[2], Wlt1, Wrt1, Wlt2, Wrt2,
        cnts, 64 + NPART, pooled, N);

    // CSR build: two-level LDS-ranked scatter + meta + partition sort
    k_scatter1<<<(E + 2047) / 2048, 256, 0, stream>>>(src, dst, bcnt1, stg1, E, NB1);
    k_scatter2<<<NB1 * SPLIT, 256, 0, stream>>>(bcnt1, stg1, pcnt, pstg);
    k_meta<<<2, 256, 0, stream>>>(pcnt, pbase, off, batch, gstart, NPART, N, G);
    k_build<<<NPART, 256, 0, stream>>>(pcnt, pstg, pbase, off, csr, N);

    // layer 0: fused L2-resident gather + register-hoisted GEMM
    k_l0fused<<<(N + 31) / 32, 256, 0, stream>>>(
        x, (const unsigned*)x7b, off, csr, L0[0], L0[1], L0[2], L0[3],
        L0[4], L0[5], L0[6], x1, N);

    // layer 1: 128 -> 128, MFMA, in-place on x1 (full-width blocks own their rows)
    k_agg128<<<((size_t)N * 16 + 255) / 256, 256, 0, stream>>>(x1, off, csr, meanb, N);
    k_mfma_layer<128, 128, true><<<dim3(NBX, 1), 256, 0, stream>>>(
        x1, meanb, Wlt1, Wrt1, L1[1], L1[3], L1[4], L1[5], L1[6], x1, N);

    // layer 2: 128 -> 256, MFMA, fp32 out into d_out x-region
    k_agg128<<<((size_t)N * 16 + 255) / 256, 256, 0, stream>>>(x1, off, csr, meanb, N);
    k_mfma_layer<128, 256, false><<<dim3(NBX, 2), 256, 0, stream>>>(
        x1, meanb, Wlt2, Wrt2, L2[1], L2[3], L2[4], L2[5], L2[6], x3, N);

    // global add pool
    k_pool<<<G * 16, 256, 0, stream>>>(x3, gstart, pooled, G);
}